// Round 7
// baseline (218.049 us; speedup 1.0000x reference)
//
#include <hip/hip_runtime.h>
#include <math.h>

#define NB 16
#define NC 256
#define NH 56
#define NW 56
#define NHW 3136
#define NHID 65
#define NK 4
#define NOC 256
#define WN 589824            // 256*256*9
#define OUT0 12845056        // 16*256*56*56

// ws header (float indices)
#define WS_POOLED 0          // [4096] (fallback path only)
#define WS_KB     4096       // [16] ints
#define WS_MAX    4112       // [1] (fallback path only)
#define WS_MAXP   4128       // [256] non-atomic maxtanh partials (mfma path)
#define WS_WQF    8192       // fallback fp32 banks [4][WN]
// byte offsets (MFMA path)
#define WQB_OFF   32768ul    // bf16 packed A-frags [4][8 ot][8 cs][18 f][64 lane][8] = 4,718,592 B
#define XP_OFF    4751360ul  // bf16 [16][58 row][58 col][256 ch] = 27,574,272 B
#define WS_NEED   32325632ul
// pooling partials in OUT scratch: [b][y][c] fp32 = 917,504 B (conv overwrites later)

typedef unsigned int u32;
typedef unsigned short u16;
typedef unsigned long long u64;
typedef __attribute__((ext_vector_type(8))) short s8v;
typedef __attribute__((ext_vector_type(16))) float f16v;

__device__ __forceinline__ u16 f2bf(float f) {
    union { float f; u32 u; } v; v.f = f;
    u32 u = v.u;
    return (u16)((u + 0x7fffu + ((u >> 16) & 1u)) >> 16);
}

__device__ __forceinline__ void gload_lds16(const void* g, void* l) {
    __builtin_amdgcn_global_load_lds((const __attribute__((address_space(1))) u32*)g,
                                     (__attribute__((address_space(3))) u32*)l, 16, 0, 0);
}

// ---------------- MFMA path: 3 kernels ----------------

// k_prep: grid 1152 x 256.
//  blocks 0..895  : (b*56+y) transpose ONE row -> xp bf16 + per-row channel sums -> scratch[b][y][c]
//  blocks 896..1151: maxtanh partials -> ws[WS_MAXP + j]
__global__ __launch_bounds__(256) void k_prep(const float* __restrict__ x,
                                              const float* __restrict__ w,
                                              float* __restrict__ ws,
                                              float* __restrict__ scratch) {
    const int tid = threadIdx.x;
    if (blockIdx.x >= 896) {                     // maxtanh partial
        int j = blockIdx.x - 896;
        float m = 0.f;
        for (int i = j * 256 + tid; i < WN; i += 65536)
            m = fmaxf(m, fabsf(tanhf(w[i])));
        for (int off = 32; off > 0; off >>= 1) m = fmaxf(m, __shfl_down(m, off, 64));
        __shared__ float part[4];
        int lane = tid & 63, wv = tid >> 6;
        if (lane == 0) part[wv] = m;
        __syncthreads();
        if (tid == 0)
            ws[WS_MAXP + j] = fmaxf(fmaxf(part[0], part[1]), fmaxf(part[2], part[3]));
        return;
    }
    const int by = blockIdx.x;                   // b*56 + y
    const int b = by / 56, y = by % 56;
    const int c16 = tid >> 4, q = tid & 15;      // 16 channels x 16 q-lanes
    __shared__ __align__(8) u16 Lbt[56 * 264];   // [w][c] pitch 264
    __shared__ float pl[256];
    u16* xp = (u16*)((char*)ws + XP_OFF);

    #pragma unroll
    for (int ci = 0; ci < 16; ++ci) {            // 16 independent iterations -> deep MLP
        int c = ci * 16 + c16;
        float4 v = make_float4(0.f, 0.f, 0.f, 0.f);
        if (q < 14) {
            v = *(const float4*)(x + ((size_t)(b * 256 + c)) * NHW + (size_t)y * 56 + q * 4);
            Lbt[(q * 4 + 0) * 264 + c] = f2bf(v.x);
            Lbt[(q * 4 + 1) * 264 + c] = f2bf(v.y);
            Lbt[(q * 4 + 2) * 264 + c] = f2bf(v.z);
            Lbt[(q * 4 + 3) * 264 + c] = f2bf(v.w);
        }
        float s = v.x + v.y + v.z + v.w;
        s += __shfl_down(s, 8, 16);
        s += __shfl_down(s, 4, 16);
        s += __shfl_down(s, 2, 16);
        s += __shfl_down(s, 1, 16);
        if (q == 0) pl[c] = s;
    }
    __syncthreads();
    scratch[(size_t)by * 256 + tid] = pl[tid];   // coalesced 1KB store
    u64* rowp = (u64*)xp + (size_t)(b * 58 + y + 1) * (58 * 64);
    for (int idx = tid; idx < 58 * 64; idx += 256) {
        int col = idx >> 6, cp = idx & 63;
        u64 v = 0ull;
        if (col >= 1 && col <= 56)
            v = *(const u64*)(Lbt + (col - 1) * 264 + cp * 4);
        rowp[idx] = v;
    }
    if (y == 0 || y == 55) {                     // zero border rows 0 / 57
        int row = (y == 0) ? 0 : 57;
        u64* brow = (u64*)xp + (size_t)(b * 58 + row) * (58 * 64);
        for (int idx = tid; idx < 58 * 64; idx += 256) brow[idx] = 0ull;
    }
}

// k_mid: grid 144 x 256. blocks 0..15: fc+argmax; 16..143: quant+pack.
__global__ __launch_bounds__(256) void k_mid(const float* __restrict__ w_fc1,
                                             const float* __restrict__ w_fc2,
                                             const float* __restrict__ b_fc2,
                                             const float* __restrict__ w,
                                             float* __restrict__ ws,
                                             const float* __restrict__ scratch,
                                             float* __restrict__ out_raw) {
    const int tid = threadIdx.x;
    if (blockIdx.x < 16) {                       // ---- fc ----
        const int b = blockIdx.x;
        __shared__ float pl[NC];
        __shared__ float hs[NHID];
        __shared__ float raws[NK];
        float p = 0.f;
        for (int y = 0; y < 56; ++y)             // coalesced across threads per y
            p += scratch[((size_t)(b * 56 + y)) * 256 + tid];
        pl[tid] = p * (1.0f / NHW);
        __syncthreads();
        if (tid < NHID) {
            float s = 0.f;
            for (int c = 0; c < NC; ++c) s = fmaf(pl[c], w_fc1[tid * NC + c], s);
            hs[tid] = fmaxf(s, 0.f);
        }
        __syncthreads();
        if (tid < NK) {
            float s = b_fc2[tid];
            for (int j = 0; j < NHID; ++j) s = fmaf(hs[j], w_fc2[tid * NHID + j], s);
            raws[tid] = s;
            out_raw[b * NK + tid] = s;
        }
        __syncthreads();
        if (tid == 0) {
            int best = 0;
            for (int k = 1; k < NK; ++k) if (raws[k] > raws[best]) best = k;
            ((int*)(ws + WS_KB))[b] = best;
        }
        return;
    }
    // ---- quant + pack ----
    __shared__ float mred[4];
    float mv = ws[WS_MAXP + tid];
    for (int off = 32; off > 0; off >>= 1) mv = fmaxf(mv, __shfl_down(mv, off, 64));
    if ((tid & 63) == 0) mred[tid >> 6] = mv;
    __syncthreads();
    const float maxt = fmaxf(fmaxf(mred[0], mred[1]), fmaxf(mred[2], mred[3]));

    u16* wqp = (u16*)((char*)ws + WQB_OFF);
    int idx = (blockIdx.x - 16) * 256 + tid;     // 128 blocks: 256 o x 128 c2
    int o = idx >> 7, c2 = idx & 127;
    int ch0 = c2 * 2;
    int cs = ch0 >> 5, cc = ch0 & 31;
    int ks2 = cc >> 4, hf = (cc >> 3) & 1, j = cc & 7;
    int n = o & 31, ot = o >> 5;
    const float* wp = w + ((size_t)o * 256 + ch0) * 9;
    float t0[9], t1[9];
    #pragma unroll
    for (int t = 0; t < 9; ++t) t0[t] = tanhf(wp[t]);
    #pragma unroll
    for (int t = 0; t < 9; ++t) t1[t] = tanhf(wp[9 + t]);
    #pragma unroll
    for (int bank = 0; bank < 4; ++bank) {
        float a = (float)(4 << bank);
        #pragma unroll
        for (int tap = 0; tap < 9; ++tap) {
            float xq0 = (t0[tap] / maxt + 1.f) * 0.5f;
            float xq1 = (t1[tap] / maxt + 1.f) * 0.5f;
            float q0 = fminf(floorf(a * xq0), a - 1.f) / a * 2.f - 1.f;
            float q1 = fminf(floorf(a * xq1), a - 1.f) / a * 2.f - 1.f;
            u32 pk = (u32)f2bf(q0) | ((u32)f2bf(q1) << 16);
            size_t off16 = ((((size_t)((bank * 8 + ot) * 8 + cs)) * 18 + tap * 2 + ks2) * 64
                            + hf * 32 + n) * 8 + j;
            *(u32*)(wqp + off16) = pk;
        }
    }
}

// Implicit-GEMM conv, mfma_f32_32x32x16_bf16.
// v6: register-budget fix + 1-tap-ahead rotation.
//  - v5 post-mortem: launch_bounds(256,2) caps unified regs at 256/wave; acc=128
//    left 8 spare -> v5's 18 buffered frags spilled (WRITE_SIZE +11MB).
//  - Now every wave owns EXACTLY 3 n-tiles (12x32 = px 0..383): acc 96 regs,
//    ~40 free for a fully-unrolled two-reg-set rotation (reads of tap t+1 issue
//    under MFMAs of tap t; compiler emits counted lgkmcnt on reg deps - no pins).
//  - Remainder px (row 6, cols 48..55 per strip = 64 px = exactly 2 MFMA tiles
//    per (b,oq)) -> 64 dedicated blocks (IDs 512..575), tail-filled.
__global__ __launch_bounds__(256, 2) void k_conv_mfma(const float* __restrict__ bias,
                                                      const float* __restrict__ ws_f,
                                                      float* __restrict__ out) {
    const int L = blockIdx.x;
    const int tid = threadIdx.x;
    const int wv = tid >> 6, lane = tid & 63;
    const int n = lane & 31, hf = lane >> 5;
    const u16* wqp = (const u16*)((const char*)ws_f + WQB_OFF);
    const u16* xp  = (const u16*)((const char*)ws_f + XP_OFF);

    __shared__ __align__(16) u16 SH[36864];      // 73728 B: Xl = SH[buf*9216], Al = SH[18432 + buf*9216]

    if (L >= 512) {
        // ---- remainder blocks: (b, oq); 64 px = 8 strips x (row 7s+6, cols 48..55) ----
        const int rb = L - 512;
        const int b = rb >> 2, oq = rb & 3;
        const int kb = ((const int*)(ws_f + WS_KB))[b];
        const u16* ab0 = wqp + (size_t)((kb * 8 + oq * 2 + 0) * 8) * (18 * 64 * 8);
        const u16* ab1 = wqp + (size_t)((kb * 8 + oq * 2 + 1) * 8) * (18 * 64 * 8);
        // lane -> px: tile tt = wv (waves 0,1 compute; 2,3 stage-only)
        const int tt = wv & 1;
        const int jj = tt * 32 + n;              // 0..63
        const int strip = jj >> 3, cc = jj & 7;
        f16v ar0 = (f16v)0.f, ar1 = (f16v)0.f;
        // LDS: Xr[8 strip][3 row][10 col][2 hf][8ch] bf16 = 7680 B in SH
        #pragma unroll 1
        for (int st = 0; st < 16; ++st) {
            for (int idx = tid; idx < 480; idx += 256) {   // 480 x 16B chunks
                int s8 = idx / 60, rem = idx % 60;
                int r = rem / 20, rem2 = rem % 20;
                int col = rem2 >> 1, hfc = rem2 & 1;
                *(s8v*)(SH + ((s8 * 3 + r) * 10 + col) * 16 + hfc * 8) =
                    *(const s8v*)(xp + ((size_t)(b * 58 + s8 * 7 + 6 + r) * 58 + (48 + col)) * 256
                                  + st * 16 + hfc * 8);
            }
            __syncthreads();
            if (wv < 2) {
                #pragma unroll
                for (int tap = 0; tap < 9; ++tap) {
                    const int r = tap / 3, s = tap % 3;
                    s8v a0 = *(const s8v*)(ab0 + (size_t)((st >> 1) * 18 + tap * 2 + (st & 1)) * 512 + lane * 8);
                    s8v a1 = *(const s8v*)(ab1 + (size_t)((st >> 1) * 18 + tap * 2 + (st & 1)) * 512 + lane * 8);
                    s8v bf = *(const s8v*)(SH + ((strip * 3 + r) * 10 + (cc + s)) * 16 + hf * 8);
                    ar0 = __builtin_amdgcn_mfma_f32_32x32x16_bf16(a0, bf, ar0, 0, 0, 0);
                    ar1 = __builtin_amdgcn_mfma_f32_32x32x16_bf16(a1, bf, ar1, 0, 0, 0);
                }
            }
            __syncthreads();
        }
        if (wv < 2) {
            const int row = strip * 7 + 6, col = 48 + cc;
            float* op = out + (size_t)b * 256 * NHW + (size_t)row * 56 + col;
            #pragma unroll
            for (int reg = 0; reg < 16; ++reg) {
                int m = (reg & 3) + 8 * (reg >> 2) + 4 * hf;
                int o0 = oq * 64 + m;
                op[(size_t)o0 * NHW] = ar0[reg] + bias[kb * NOC + o0];
                op[(size_t)(o0 + 32) * NHW] = ar1[reg] + bias[kb * NOC + o0 + 32];
            }
        }
        return;
    }

    // ---- main blocks ----
    const int xcd = L & 7, slot = L >> 3;        // XCD-chunked swizzle (512 % 8 == 0)
    const int oq = slot >> 4;                    // 0..3
    const int pair = xcd * 16 + (slot & 15);     // b*8 + strip
    const int b = pair >> 3, strip = pair & 7;
    const int r0 = strip * 7;
    const int kb = ((const int*)(ws_f + WS_KB))[b];

    // wave owns n-tiles {3wv, 3wv+1, 3wv+2} of 12 (px 0..383)
    int bofs0, bofs1, bofs2;
    {
        int p0 = (wv * 3 + 0) * 32 + n, p1 = p0 + 32, p2 = p0 + 64;
        bofs0 = (p0 / 56) * 2048 + hf * 1024 + (p0 % 56) * 16;
        bofs1 = (p1 / 56) * 2048 + hf * 1024 + (p1 % 56) * 16;
        bofs2 = (p2 / 56) * 2048 + hf * 1024 + (p2 % 56) * 16;
    }
    const int colc = (lane < 58) ? lane : 57;
    const u16* xsrc = xp + (((size_t)(b * 58 + r0)) * 58 + colc) * 256;
    const u16* ab0 = wqp + (size_t)((kb * 8 + oq * 2 + 0) * 8) * (18 * 64 * 8);
    const u16* ab1 = wqp + (size_t)((kb * 8 + oq * 2 + 1) * 8) * (18 * 64 * 8);

    f16v a00 = (f16v)0.f, a01 = (f16v)0.f, a02 = (f16v)0.f;   // acc o-tile 0 x 3 n-tiles
    f16v a10 = (f16v)0.f, a11 = (f16v)0.f, a12 = (f16v)0.f;   // acc o-tile 1

    // 36 segs of 1KB per step (18 X + 18 A); each wave stages exactly 9.
#define STAGE(stn, bn)                                                                   \
    {                                                                                    \
        const int csn = (stn) >> 1, ksn = (stn) & 1;                                     \
        _Pragma("unroll")                                                                \
        for (int i = 0; i < 9; ++i) {                                                    \
            int seg = wv * 9 + i;                                                        \
            if (seg < 18) {                                                              \
                gload_lds16(xsrc + (size_t)(seg >> 1) * (58 * 256) + (stn) * 16 + (seg & 1) * 8, \
                            (void*)(SH + (bn) * 9216 + seg * 512));                      \
            } else {                                                                     \
                int aa = seg - 18;                                                       \
                int tile = (aa >= 9) ? 1 : 0;                                            \
                int tap = aa - tile * 9;                                                 \
                const u16* ab = tile ? ab1 : ab0;                                        \
                gload_lds16(ab + (size_t)(csn * 18 + tap * 2 + ksn) * 512 + lane * 8,    \
                            (void*)(SH + 18432 + (bn) * 9216 + aa * 512));               \
            }                                                                            \
        }                                                                                \
    }

    STAGE(0, 0);                                 // 9 loads in flight

    #pragma unroll 1
    for (int st = 0; st < 16; ++st) {
        int pb = st & 1;
        if (st < 15) {
            STAGE(st + 1, pb ^ 1);               // +9 -> <=18 outstanding
            asm volatile("s_waitcnt vmcnt(9)" ::: "memory");   // stage(st) done; next 9 in flight
        } else {
            asm volatile("s_waitcnt vmcnt(0)" ::: "memory");
        }
        __builtin_amdgcn_s_barrier();            // buf[pb] staged & visible
        __builtin_amdgcn_s_setprio(1);
        const u16* AB = SH + 18432 + pb * 9216;
        const char* XB = (const char*)(SH + pb * 9216);
        // 1-tap-ahead rotation: reads of tap t+1 issue under MFMAs of tap t.
        s8v qa0A, qa1A, qb0A, qb1A, qb2A, qa0B, qa1B, qb0B, qb1B, qb2B;
#define RD(tp, S)                                                                        \
        qa0##S = *(const s8v*)(AB + (tp) * 512 + lane * 8);                              \
        qa1##S = *(const s8v*)(AB + (9 + (tp)) * 512 + lane * 8);                        \
        qb0##S = *(const s8v*)(XB + bofs0 + ((tp) / 3) * 2048 + ((tp) % 3) * 16);        \
        qb1##S = *(const s8v*)(XB + bofs1 + ((tp) / 3) * 2048 + ((tp) % 3) * 16);        \
        qb2##S = *(const s8v*)(XB + bofs2 + ((tp) / 3) * 2048 + ((tp) % 3) * 16);
#define MM(S)                                                                            \
        a00 = __builtin_amdgcn_mfma_f32_32x32x16_bf16(qa0##S, qb0##S, a00, 0, 0, 0);     \
        a10 = __builtin_amdgcn_mfma_f32_32x32x16_bf16(qa1##S, qb0##S, a10, 0, 0, 0);     \
        a01 = __builtin_amdgcn_mfma_f32_32x32x16_bf16(qa0##S, qb1##S, a01, 0, 0, 0);     \
        a11 = __builtin_amdgcn_mfma_f32_32x32x16_bf16(qa1##S, qb1##S, a11, 0, 0, 0);     \
        a02 = __builtin_amdgcn_mfma_f32_32x32x16_bf16(qa0##S, qb2##S, a02, 0, 0, 0);     \
        a12 = __builtin_amdgcn_mfma_f32_32x32x16_bf16(qa1##S, qb2##S, a12, 0, 0, 0);
        RD(0, A);
        RD(1, B); MM(A);
        RD(2, A); MM(B);
        RD(3, B); MM(A);
        RD(4, A); MM(B);
        RD(5, B); MM(A);
        RD(6, A); MM(B);
        RD(7, B); MM(A);
        RD(8, A); MM(B);
        MM(A);
#undef RD
#undef MM
        __builtin_amdgcn_s_setprio(0);
        asm volatile("" ::: "memory");
        __builtin_amdgcn_s_barrier();            // all reads of buf[pb] done -> st+2 may overwrite
    }
#undef STAGE

    {
        const int p0 = wv * 3 * 32 + n;
        #pragma unroll
        for (int t = 0; t < 3; ++t) {
            const int p = p0 + t * 32;
            const int pr = p / 56, pc = p % 56;
            float* op = out + (size_t)b * 256 * NHW + (size_t)(r0 + pr) * 56 + pc;
            const f16v accA = (t == 0) ? a00 : (t == 1) ? a01 : a02;
            const f16v accB = (t == 0) ? a10 : (t == 1) ? a11 : a12;
            #pragma unroll
            for (int reg = 0; reg < 16; ++reg) {
                int m = (reg & 3) + 8 * (reg >> 2) + 4 * hf;
                int o0 = oq * 64 + m;
                op[(size_t)o0 * NHW] = accA[reg] + bias[kb * NOC + o0];
                op[(size_t)(o0 + 32) * NHW] = accB[reg] + bias[kb * NOC + o0 + 32];
            }
        }
    }
}

// ---------------- fallback fp32 path ----------------

__global__ __launch_bounds__(256) void k_pool(const float* __restrict__ x,
                                              float* __restrict__ ws) {
    int plane = blockIdx.x;
    const float* p = x + (size_t)plane * NHW;
    float s = 0.f;
    for (int i = threadIdx.x; i < NHW; i += 256) s += p[i];
    for (int off = 32; off > 0; off >>= 1) s += __shfl_down(s, off, 64);
    __shared__ float part[4];
    int lane = threadIdx.x & 63, wv = threadIdx.x >> 6;
    if (lane == 0) part[wv] = s;
    __syncthreads();
    if (threadIdx.x == 0)
        ws[WS_POOLED + plane] = part[0] + part[1] + part[2] + part[3];
}

__global__ __launch_bounds__(256) void k_fc(const float* __restrict__ w_fc1,
                                            const float* __restrict__ w_fc2,
                                            const float* __restrict__ b_fc2,
                                            float* __restrict__ ws,
                                            float* __restrict__ out_raw) {
    __shared__ float pl[NB * NC];
    __shared__ float hs[NB][NHID];
    __shared__ float raws[NB][NK];
    for (int i = threadIdx.x; i < NB * NC; i += 256)
        pl[i] = ws[WS_POOLED + i] * (1.0f / NHW);
    __syncthreads();
    for (int idx = threadIdx.x; idx < NB * NHID; idx += 256) {
        int b = idx / NHID, j = idx % NHID;
        float s = 0.f;
        for (int c = 0; c < NC; ++c) s = fmaf(pl[b * NC + c], w_fc1[j * NC + c], s);
        hs[b][j] = fmaxf(s, 0.f);
    }
    __syncthreads();
    if (threadIdx.x < NB * NK) {
        int b = threadIdx.x / NK, k = threadIdx.x % NK;
        float s = b_fc2[k];
        for (int j = 0; j < NHID; ++j) s = fmaf(hs[b][j], w_fc2[k * NHID + j], s);
        raws[b][k] = s;
        out_raw[b * NK + k] = s;
    }
    __syncthreads();
    if (threadIdx.x < NB) {
        int best = 0;
        for (int k = 1; k < NK; ++k)
            if (raws[threadIdx.x][k] > raws[threadIdx.x][best]) best = k;
        ((int*)(ws + WS_KB))[threadIdx.x] = best;
    }
}

__global__ __launch_bounds__(256) void k_maxtanh(const float* __restrict__ w,
                                                 float* __restrict__ ws) {
    float m = 0.f;
    for (int i = blockIdx.x * 256 + threadIdx.x; i < WN; i += gridDim.x * 256)
        m = fmaxf(m, fabsf(tanhf(w[i])));
    for (int off = 32; off > 0; off >>= 1) m = fmaxf(m, __shfl_down(m, off, 64));
    __shared__ float part[4];
    int lane = threadIdx.x & 63, wv = threadIdx.x >> 6;
    if (lane == 0) part[wv] = m;
    __syncthreads();
    if (threadIdx.x == 0) {
        float t = fmaxf(fmaxf(part[0], part[1]), fmaxf(part[2], part[3]));
        atomicMax((unsigned int*)ws + WS_MAX, __float_as_uint(t));
    }
}

__global__ __launch_bounds__(256) void k_quant(const float* __restrict__ w,
                                               float* __restrict__ ws) {
    float maxt = __uint_as_float(((const unsigned int*)ws)[WS_MAX]);
    float* wqf = ws + WS_WQF;
    for (int i = blockIdx.x * 256 + threadIdx.x; i < WN; i += gridDim.x * 256) {
        float t = tanhf(w[i]);
        float xq = (t / maxt + 1.0f) * 0.5f;
        #pragma unroll
        for (int k = 0; k < NK; ++k) {
            float a = (float)(4 << k);
            float q = fminf(floorf(a * xq), a - 1.0f) / a;
            wqf[(size_t)k * WN + i] = q * 2.0f - 1.0f;
        }
    }
}

__global__ __launch_bounds__(256) void k_conv(const float* __restrict__ x,
                                              const float* __restrict__ bias,
                                              const float* __restrict__ ws,
                                              float* __restrict__ out) {
    const int o_base = blockIdx.x * 16;
    const int row_base = blockIdx.y * 7;
    const int b = blockIdx.z;
    const int tid = threadIdx.x;
    const int w = tid & 63;
    const int og = tid >> 6;
    const int wc = (w < 56) ? w : 55;
    const int kb = ((const int*)(ws + WS_KB))[b];
    const float* wqf = ws + WS_WQF + (size_t)kb * WN;

    __shared__ float Xl[8][9][58];
    __shared__ float Wl[16][72];

    float acc[4][7];
    #pragma unroll
    for (int i = 0; i < 4; ++i)
        #pragma unroll
        for (int j = 0; j < 7; ++j) acc[i][j] = 0.f;

    for (int c0 = 0; c0 < NC; c0 += 8) {
        for (int idx = tid; idx < 1152; idx += 256) {
            int o = idx / 72, rem = idx - o * 72;
            Wl[o][rem] = wqf[(size_t)(o_base + o) * 2304 + c0 * 9 + rem];
        }
        for (int idx = tid; idx < 4176; idx += 256) {
            int c = idx / 522, rem = idx - c * 522;
            int ly = rem / 58, lx = rem - ly * 58;
            int gy = row_base - 1 + ly, gx = lx - 1;
            float v = 0.f;
            if (gy >= 0 && gy < NH && (unsigned)gx < (unsigned)NW)
                v = x[(((size_t)b * NC + c0 + c) * NH + gy) * NW + gx];
            Xl[c][ly][lx] = v;
        }
        __syncthreads();
        #pragma unroll 1
        for (int c = 0; c < 8; ++c) {
            float xv[9][3];
            #pragma unroll
            for (int ly = 0; ly < 9; ++ly)
                #pragma unroll
                for (int s = 0; s < 3; ++s)
                    xv[ly][s] = Xl[c][ly][wc + s];
            float wvv[4][9];
            #pragma unroll
            for (int i = 0; i < 4; ++i)
                #pragma unroll
                for (int t = 0; t < 9; ++t)
                    wvv[i][t] = Wl[og * 4 + i][c * 9 + t];
            #pragma unroll
            for (int i = 0; i < 4; ++i)
                #pragma unroll
                for (int j = 0; j < 7; ++j)
                    #pragma unroll
                    for (int r = 0; r < 3; ++r)
                        #pragma unroll
                        for (int s = 0; s < 3; ++s)
                            acc[i][j] = fmaf(wvv[i][r * 3 + s], xv[j + r][s], acc[i][j]);
        }
        __syncthreads();
    }

    if (w < 56) {
        #pragma unroll
        for (int i = 0; i < 4; ++i) {
            int o = o_base + og * 4 + i;
            float bb = bias[kb * NOC + o];
            #pragma unroll
            for (int j = 0; j < 7; ++j)
                out[(((size_t)b * NOC + o) * NH + (row_base + j)) * NW + w] = acc[i][j] + bb;
        }
    }
}

extern "C" void kernel_launch(void* const* d_in, const int* in_sizes, int n_in,
                              void* d_out, int out_size, void* d_ws, size_t ws_size,
                              hipStream_t stream) {
    const float* x      = (const float*)d_in[0];
    const float* w_fc1  = (const float*)d_in[1];
    const float* w_fc2  = (const float*)d_in[2];
    const float* b_fc2  = (const float*)d_in[3];
    const float* weight = (const float*)d_in[4];
    const float* bias   = (const float*)d_in[5];
    float* out = (float*)d_out;
    float* ws  = (float*)d_ws;

    if (ws_size >= WS_NEED) {
        hipLaunchKernelGGL(k_prep, dim3(1152), dim3(256), 0, stream, x, weight, ws, out);
        hipLaunchKernelGGL(k_mid, dim3(144), dim3(256), 0, stream,
                           w_fc1, w_fc2, b_fc2, weight, ws, out, out + OUT0);
        hipLaunchKernelGGL(k_conv_mfma, dim3(576), dim3(256), 0, stream, bias, ws, out);
    } else {
        hipLaunchKernelGGL(k_pool, dim3(NB * NC), dim3(256), 0, stream, x, ws);
        hipLaunchKernelGGL(k_fc, dim3(1), dim3(256), 0, stream,
                           w_fc1, w_fc2, b_fc2, ws, out + OUT0);
        hipLaunchKernelGGL(k_maxtanh, dim3(256), dim3(256), 0, stream, weight, ws);
        hipLaunchKernelGGL(k_quant, dim3(512), dim3(256), 0, stream, weight, ws);
        hipLaunchKernelGGL(k_conv, dim3(16, 8, NB), dim3(256), 0, stream, x, bias, ws, out);
    }
}

// Round 8
// 186.627 us; speedup vs baseline: 1.1684x; 1.1684x over previous
//
#include <hip/hip_runtime.h>
#include <math.h>

#define NB 16
#define NC 256
#define NH 56
#define NW 56
#define NHW 3136
#define NHID 65
#define NK 4
#define NOC 256
#define WN 589824            // 256*256*9
#define OUT0 12845056        // 16*256*56*56

// ws header (float indices)
#define WS_POOLED 0          // [4096] (fallback path only)
#define WS_KB     4096       // [16] ints
#define WS_MAX    4112       // [1] (fallback path only)
#define WS_MAXP   4128       // [256] non-atomic maxtanh partials (mfma path)
#define WS_WQF    8192       // fallback fp32 banks [4][WN]
// byte offsets (MFMA path)
#define WQB_OFF   32768ul    // bf16 packed A-frags [4][8 ot][8 cs][18 f][64 lane][8] = 4,718,592 B
#define XP_OFF    4751360ul  // bf16 [16][58 row][58 col][256 ch] = 27,574,272 B
#define WS_NEED   32325632ul
// pooling partials in OUT scratch: [b][y][c] fp32 = 917,504 B (conv overwrites later)

typedef unsigned int u32;
typedef unsigned short u16;
typedef unsigned long long u64;
typedef __attribute__((ext_vector_type(8))) short s8v;
typedef __attribute__((ext_vector_type(16))) float f16v;

__device__ __forceinline__ u16 f2bf(float f) {
    union { float f; u32 u; } v; v.f = f;
    u32 u = v.u;
    return (u16)((u + 0x7fffu + ((u >> 16) & 1u)) >> 16);
}

__device__ __forceinline__ void gload_lds16(const void* g, void* l) {
    __builtin_amdgcn_global_load_lds((const __attribute__((address_space(1))) u32*)g,
                                     (__attribute__((address_space(3))) u32*)l, 16, 0, 0);
}

// ---------------- MFMA path: 3 kernels ----------------

// k_prep: grid 1152 x 256.
//  blocks 0..895  : (b*56+y) transpose ONE row -> xp bf16 + per-row channel sums -> scratch[b][y][c]
//  blocks 896..1151: maxtanh partials -> ws[WS_MAXP + j]
__global__ __launch_bounds__(256) void k_prep(const float* __restrict__ x,
                                              const float* __restrict__ w,
                                              float* __restrict__ ws,
                                              float* __restrict__ scratch) {
    const int tid = threadIdx.x;
    if (blockIdx.x >= 896) {                     // maxtanh partial
        int j = blockIdx.x - 896;
        float m = 0.f;
        for (int i = j * 256 + tid; i < WN; i += 65536)
            m = fmaxf(m, fabsf(tanhf(w[i])));
        for (int off = 32; off > 0; off >>= 1) m = fmaxf(m, __shfl_down(m, off, 64));
        __shared__ float part[4];
        int lane = tid & 63, wv = tid >> 6;
        if (lane == 0) part[wv] = m;
        __syncthreads();
        if (tid == 0)
            ws[WS_MAXP + j] = fmaxf(fmaxf(part[0], part[1]), fmaxf(part[2], part[3]));
        return;
    }
    const int by = blockIdx.x;                   // b*56 + y
    const int b = by / 56, y = by % 56;
    const int c16 = tid >> 4, q = tid & 15;      // 16 channels x 16 q-lanes
    __shared__ __align__(8) u16 Lbt[56 * 264];   // [w][c] pitch 264
    __shared__ float pl[256];
    u16* xp = (u16*)((char*)ws + XP_OFF);

    #pragma unroll
    for (int ci = 0; ci < 16; ++ci) {            // 16 independent iterations -> deep MLP
        int c = ci * 16 + c16;
        float4 v = make_float4(0.f, 0.f, 0.f, 0.f);
        if (q < 14) {
            v = *(const float4*)(x + ((size_t)(b * 256 + c)) * NHW + (size_t)y * 56 + q * 4);
            Lbt[(q * 4 + 0) * 264 + c] = f2bf(v.x);
            Lbt[(q * 4 + 1) * 264 + c] = f2bf(v.y);
            Lbt[(q * 4 + 2) * 264 + c] = f2bf(v.z);
            Lbt[(q * 4 + 3) * 264 + c] = f2bf(v.w);
        }
        float s = v.x + v.y + v.z + v.w;
        s += __shfl_down(s, 8, 16);
        s += __shfl_down(s, 4, 16);
        s += __shfl_down(s, 2, 16);
        s += __shfl_down(s, 1, 16);
        if (q == 0) pl[c] = s;
    }
    __syncthreads();
    scratch[(size_t)by * 256 + tid] = pl[tid];   // coalesced 1KB store
    u64* rowp = (u64*)xp + (size_t)(b * 58 + y + 1) * (58 * 64);
    for (int idx = tid; idx < 58 * 64; idx += 256) {
        int col = idx >> 6, cp = idx & 63;
        u64 v = 0ull;
        if (col >= 1 && col <= 56)
            v = *(const u64*)(Lbt + (col - 1) * 264 + cp * 4);
        rowp[idx] = v;
    }
    if (y == 0 || y == 55) {                     // zero border rows 0 / 57
        int row = (y == 0) ? 0 : 57;
        u64* brow = (u64*)xp + (size_t)(b * 58 + row) * (58 * 64);
        for (int idx = tid; idx < 58 * 64; idx += 256) brow[idx] = 0ull;
    }
}

// k_mid: grid 144 x 256. blocks 0..15: fc+argmax; 16..143: quant+pack.
__global__ __launch_bounds__(256) void k_mid(const float* __restrict__ w_fc1,
                                             const float* __restrict__ w_fc2,
                                             const float* __restrict__ b_fc2,
                                             const float* __restrict__ w,
                                             float* __restrict__ ws,
                                             const float* __restrict__ scratch,
                                             float* __restrict__ out_raw) {
    const int tid = threadIdx.x;
    if (blockIdx.x < 16) {                       // ---- fc ----
        const int b = blockIdx.x;
        __shared__ float pl[NC];
        __shared__ float hs[NHID];
        __shared__ float raws[NK];
        float p = 0.f;
        for (int y = 0; y < 56; ++y)             // coalesced across threads per y
            p += scratch[((size_t)(b * 56 + y)) * 256 + tid];
        pl[tid] = p * (1.0f / NHW);
        __syncthreads();
        if (tid < NHID) {
            float s = 0.f;
            for (int c = 0; c < NC; ++c) s = fmaf(pl[c], w_fc1[tid * NC + c], s);
            hs[tid] = fmaxf(s, 0.f);
        }
        __syncthreads();
        if (tid < NK) {
            float s = b_fc2[tid];
            for (int j = 0; j < NHID; ++j) s = fmaf(hs[j], w_fc2[tid * NHID + j], s);
            raws[tid] = s;
            out_raw[b * NK + tid] = s;
        }
        __syncthreads();
        if (tid == 0) {
            int best = 0;
            for (int k = 1; k < NK; ++k) if (raws[k] > raws[best]) best = k;
            ((int*)(ws + WS_KB))[b] = best;
        }
        return;
    }
    // ---- quant + pack ----
    __shared__ float mred[4];
    float mv = ws[WS_MAXP + tid];
    for (int off = 32; off > 0; off >>= 1) mv = fmaxf(mv, __shfl_down(mv, off, 64));
    if ((tid & 63) == 0) mred[tid >> 6] = mv;
    __syncthreads();
    const float maxt = fmaxf(fmaxf(mred[0], mred[1]), fmaxf(mred[2], mred[3]));

    u16* wqp = (u16*)((char*)ws + WQB_OFF);
    int idx = (blockIdx.x - 16) * 256 + tid;     // 128 blocks: 256 o x 128 c2
    int o = idx >> 7, c2 = idx & 127;
    int ch0 = c2 * 2;
    int cs = ch0 >> 5, cc = ch0 & 31;
    int ks2 = cc >> 4, hf = (cc >> 3) & 1, j = cc & 7;
    int n = o & 31, ot = o >> 5;
    const float* wp = w + ((size_t)o * 256 + ch0) * 9;
    float t0[9], t1[9];
    #pragma unroll
    for (int t = 0; t < 9; ++t) t0[t] = tanhf(wp[t]);
    #pragma unroll
    for (int t = 0; t < 9; ++t) t1[t] = tanhf(wp[9 + t]);
    #pragma unroll
    for (int bank = 0; bank < 4; ++bank) {
        float a = (float)(4 << bank);
        #pragma unroll
        for (int tap = 0; tap < 9; ++tap) {
            float xq0 = (t0[tap] / maxt + 1.f) * 0.5f;
            float xq1 = (t1[tap] / maxt + 1.f) * 0.5f;
            float q0 = fminf(floorf(a * xq0), a - 1.f) / a * 2.f - 1.f;
            float q1 = fminf(floorf(a * xq1), a - 1.f) / a * 2.f - 1.f;
            u32 pk = (u32)f2bf(q0) | ((u32)f2bf(q1) << 16);
            size_t off16 = ((((size_t)((bank * 8 + ot) * 8 + cs)) * 18 + tap * 2 + ks2) * 64
                            + hf * 32 + n) * 8 + j;
            *(u32*)(wqp + off16) = pk;
        }
    }
}

// Implicit-GEMM conv, mfma_f32_32x32x16_bf16.
// v7: occupancy lever. v4 (4 waves, acc 104-128) sits at 2.1x the LDS-BW floor
// (189KB/block-step at 85B/cy = 4.4k cy vs 10.8k measured) because regs cap
// residency at 2 waves/SIMD. v1's 8-wave geometry had acc=64, VGPR=60 ->
// <=128 total -> 4 waves/SIMD (16 waves/CU, m69), but died on inline global A.
// Hybrid: 8 waves x {2,2,2,2,2,1,1,1} n-tiles (v1) + A&X staged in LDS with
// counted vmcnt + setprio (v4). A-LDS redundancy doubles (261KB/block-step,
// floor ~47us) but overlap factor should drop 2.1x -> ~1.3x.
// Waves stage {5,5,5,5,4,4,4,4} of 36 segs; per-wave counted vmcnt(5)/(4).
__global__ __launch_bounds__(512, 4) void k_conv_mfma(const float* __restrict__ bias,
                                                      const float* __restrict__ ws_f,
                                                      float* __restrict__ out) {
    const int L = blockIdx.x;
    const int xcd = L & 7, slot = L >> 3;        // XCD-chunked swizzle (512 % 8 == 0)
    const int oq = slot >> 4;                    // 0..3
    const int pair = xcd * 16 + (slot & 15);     // b*8 + strip
    const int b = pair >> 3, strip = pair & 7;
    const int r0 = strip * 7;
    const int tid = threadIdx.x;
    const int wv = tid >> 6, lane = tid & 63;
    const int n = lane & 31, hf = lane >> 5;
    const int vw = (wv + (slot & 7)) & 7;        // rotate tile roles across blocks
    const int ntile = (vw < 5) ? 2 : 1;
    const int t0 = (vw < 5) ? vw * 2 : 10 + (vw - 5);
    const int kb = ((const int*)(ws_f + WS_KB))[b];
    const u16* wqp = (const u16*)((const char*)ws_f + WQB_OFF);
    const u16* xp  = (const u16*)((const char*)ws_f + XP_OFF);

    __shared__ __align__(16) u16 Xl[2][9216];    // [buf][9 row][2 oct][64 lane][8] = 2x18 KB
    __shared__ __align__(16) u16 Al[2][9216];    // [buf][2 tile][9 tap][64 lane][8] = 2x18 KB

    int bofs[2];
    #pragma unroll
    for (int t = 0; t < 2; ++t) {
        int p = (t0 + t) * 32 + n;
        if (t >= ntile || p > 391) p = 391;      // clamp: in-bounds dummy read
        int pr = p / 56, pc = p - pr * 56;
        bofs[t] = pr * 2048 + hf * 1024 + pc * 16;   // row stride = 2 oct x 1KB
    }
    const int colc = (lane < 58) ? lane : 57;
    const u16* xsrc = xp + (((size_t)(b * 58 + r0)) * 58 + colc) * 256;
    const u16* ab0 = wqp + (size_t)((kb * 8 + oq * 2 + 0) * 8) * (18 * 64 * 8);
    const u16* ab1 = wqp + (size_t)((kb * 8 + oq * 2 + 1) * 8) * (18 * 64 * 8);

    f16v acc0[2], acc1[2];
    #pragma unroll
    for (int t = 0; t < 2; ++t) { acc0[t] = (f16v)0.f; acc1[t] = (f16v)0.f; }

    // 36 segs of 1KB per step (18 X + 18 A); waves stage {5,5,5,5,4,4,4,4}.
    // X seg: row = seg>>1, oct = seg&1. A seg: aa = seg-18, tile = aa/9, tap = aa%9.
    const int sbase = (wv < 4) ? wv * 5 : 20 + (wv - 4) * 4;
    const int scnt  = (wv < 4) ? 5 : 4;
#define STAGE(stn, bn)                                                                   \
    {                                                                                    \
        const int csn = (stn) >> 1, ksn = (stn) & 1;                                     \
        _Pragma("unroll")                                                                \
        for (int i = 0; i < 5; ++i)                                                      \
            if (i < scnt) {                                                              \
                int seg = sbase + i;                                                     \
                if (seg < 18) {                                                          \
                    gload_lds16(xsrc + (size_t)(seg >> 1) * (58 * 256) + (stn) * 16 + (seg & 1) * 8, \
                                (void*)(&Xl[bn][seg * 512]));                            \
                } else {                                                                 \
                    int aa = seg - 18;                                                   \
                    int tile = (aa >= 9) ? 1 : 0;                                        \
                    int tap = aa - tile * 9;                                             \
                    const u16* ab = tile ? ab1 : ab0;                                    \
                    gload_lds16(ab + (size_t)(csn * 18 + tap * 2 + ksn) * 512 + lane * 8, \
                                (void*)(&Al[bn][aa * 512]));                             \
                }                                                                        \
            }                                                                            \
    }

    STAGE(0, 0);                                 // scnt loads in flight

    #pragma unroll 1
    for (int st = 0; st < 16; ++st) {
        int pb = st & 1;
        if (st < 15) {
            STAGE(st + 1, pb ^ 1);               // +scnt -> <=2*scnt outstanding
            // wait only stage(st)'s scnt; stage(st+1)'s stay in flight across barrier
            if (wv < 4) { asm volatile("s_waitcnt vmcnt(5)" ::: "memory"); }
            else        { asm volatile("s_waitcnt vmcnt(4)" ::: "memory"); }
        } else {
            asm volatile("s_waitcnt vmcnt(0)" ::: "memory");
        }
        __builtin_amdgcn_s_barrier();            // buf[pb] staged & visible
        __builtin_amdgcn_s_setprio(1);
        const u16* AB = &Al[pb][0];
        const char* XB = (const char*)&Xl[pb][0];
        #pragma unroll
        for (int tap = 0; tap < 9; ++tap) {
            s8v a0 = *(const s8v*)(AB + tap * 512 + lane * 8);
            s8v a1 = *(const s8v*)(AB + (9 + tap) * 512 + lane * 8);
            const int r = tap / 3, s = tap % 3;
            const int coff = r * 2048 + s * 16;
            #pragma unroll
            for (int t = 0; t < 2; ++t)
                if (t < ntile) {
                    s8v bf = *(const s8v*)(XB + bofs[t] + coff);
                    acc0[t] = __builtin_amdgcn_mfma_f32_32x32x16_bf16(a0, bf, acc0[t], 0, 0, 0);
                    acc1[t] = __builtin_amdgcn_mfma_f32_32x32x16_bf16(a1, bf, acc1[t], 0, 0, 0);
                }
        }
        __builtin_amdgcn_s_setprio(0);
        asm volatile("" ::: "memory");
        __builtin_amdgcn_s_barrier();            // all reads of buf[pb] done -> st+2 may overwrite
    }
#undef STAGE

    #pragma unroll
    for (int t = 0; t < 2; ++t)
        if (t < ntile) {
            int p = (t0 + t) * 32 + n;
            if (p < 392) {
                int pr = p / 56, pc = p - pr * 56;
                float* op = out + (size_t)b * 256 * NHW + (size_t)(r0 + pr) * 56 + pc;
                #pragma unroll
                for (int reg = 0; reg < 16; ++reg) {
                    int m = (reg & 3) + 8 * (reg >> 2) + 4 * hf;
                    int o0 = oq * 64 + m;
                    op[(size_t)o0 * NHW] = acc0[t][reg] + bias[kb * NOC + o0];
                    op[(size_t)(o0 + 32) * NHW] = acc1[t][reg] + bias[kb * NOC + o0 + 32];
                }
            }
        }
}

// ---------------- fallback fp32 path ----------------

__global__ __launch_bounds__(256) void k_pool(const float* __restrict__ x,
                                              float* __restrict__ ws) {
    int plane = blockIdx.x;
    const float* p = x + (size_t)plane * NHW;
    float s = 0.f;
    for (int i = threadIdx.x; i < NHW; i += 256) s += p[i];
    for (int off = 32; off > 0; off >>= 1) s += __shfl_down(s, off, 64);
    __shared__ float part[4];
    int lane = threadIdx.x & 63, wv = threadIdx.x >> 6;
    if (lane == 0) part[wv] = s;
    __syncthreads();
    if (threadIdx.x == 0)
        ws[WS_POOLED + plane] = part[0] + part[1] + part[2] + part[3];
}

__global__ __launch_bounds__(256) void k_fc(const float* __restrict__ w_fc1,
                                            const float* __restrict__ w_fc2,
                                            const float* __restrict__ b_fc2,
                                            float* __restrict__ ws,
                                            float* __restrict__ out_raw) {
    __shared__ float pl[NB * NC];
    __shared__ float hs[NB][NHID];
    __shared__ float raws[NB][NK];
    for (int i = threadIdx.x; i < NB * NC; i += 256)
        pl[i] = ws[WS_POOLED + i] * (1.0f / NHW);
    __syncthreads();
    for (int idx = threadIdx.x; idx < NB * NHID; idx += 256) {
        int b = idx / NHID, j = idx % NHID;
        float s = 0.f;
        for (int c = 0; c < NC; ++c) s = fmaf(pl[b * NC + c], w_fc1[j * NC + c], s);
        hs[b][j] = fmaxf(s, 0.f);
    }
    __syncthreads();
    if (threadIdx.x < NB * NK) {
        int b = threadIdx.x / NK, k = threadIdx.x % NK;
        float s = b_fc2[k];
        for (int j = 0; j < NHID; ++j) s = fmaf(hs[b][j], w_fc2[k * NHID + j], s);
        raws[b][k] = s;
        out_raw[b * NK + k] = s;
    }
    __syncthreads();
    if (threadIdx.x < NB) {
        int best = 0;
        for (int k = 1; k < NK; ++k)
            if (raws[threadIdx.x][k] > raws[threadIdx.x][best]) best = k;
        ((int*)(ws + WS_KB))[threadIdx.x] = best;
    }
}

__global__ __launch_bounds__(256) void k_maxtanh(const float* __restrict__ w,
                                                 float* __restrict__ ws) {
    float m = 0.f;
    for (int i = blockIdx.x * 256 + threadIdx.x; i < WN; i += gridDim.x * 256)
        m = fmaxf(m, fabsf(tanhf(w[i])));
    for (int off = 32; off > 0; off >>= 1) m = fmaxf(m, __shfl_down(m, off, 64));
    __shared__ float part[4];
    int lane = threadIdx.x & 63, wv = threadIdx.x >> 6;
    if (lane == 0) part[wv] = m;
    __syncthreads();
    if (threadIdx.x == 0) {
        float t = fmaxf(fmaxf(part[0], part[1]), fmaxf(part[2], part[3]));
        atomicMax((unsigned int*)ws + WS_MAX, __float_as_uint(t));
    }
}

__global__ __launch_bounds__(256) void k_quant(const float* __restrict__ w,
                                               float* __restrict__ ws) {
    float maxt = __uint_as_float(((const unsigned int*)ws)[WS_MAX]);
    float* wqf = ws + WS_WQF;
    for (int i = blockIdx.x * 256 + threadIdx.x; i < WN; i += gridDim.x * 256) {
        float t = tanhf(w[i]);
        float xq = (t / maxt + 1.0f) * 0.5f;
        #pragma unroll
        for (int k = 0; k < NK; ++k) {
            float a = (float)(4 << k);
            float q = fminf(floorf(a * xq), a - 1.0f) / a;
            wqf[(size_t)k * WN + i] = q * 2.0f - 1.0f;
        }
    }
}

__global__ __launch_bounds__(256) void k_conv(const float* __restrict__ x,
                                              const float* __restrict__ bias,
                                              const float* __restrict__ ws,
                                              float* __restrict__ out) {
    const int o_base = blockIdx.x * 16;
    const int row_base = blockIdx.y * 7;
    const int b = blockIdx.z;
    const int tid = threadIdx.x;
    const int w = tid & 63;
    const int og = tid >> 6;
    const int wc = (w < 56) ? w : 55;
    const int kb = ((const int*)(ws + WS_KB))[b];
    const float* wqf = ws + WS_WQF + (size_t)kb * WN;

    __shared__ float Xl[8][9][58];
    __shared__ float Wl[16][72];

    float acc[4][7];
    #pragma unroll
    for (int i = 0; i < 4; ++i)
        #pragma unroll
        for (int j = 0; j < 7; ++j) acc[i][j] = 0.f;

    for (int c0 = 0; c0 < NC; c0 += 8) {
        for (int idx = tid; idx < 1152; idx += 256) {
            int o = idx / 72, rem = idx - o * 72;
            Wl[o][rem] = wqf[(size_t)(o_base + o) * 2304 + c0 * 9 + rem];
        }
        for (int idx = tid; idx < 4176; idx += 256) {
            int c = idx / 522, rem = idx - c * 522;
            int ly = rem / 58, lx = rem - ly * 58;
            int gy = row_base - 1 + ly, gx = lx - 1;
            float v = 0.f;
            if (gy >= 0 && gy < NH && (unsigned)gx < (unsigned)NW)
                v = x[(((size_t)b * NC + c0 + c) * NH + gy) * NW + gx];
            Xl[c][ly][lx] = v;
        }
        __syncthreads();
        #pragma unroll 1
        for (int c = 0; c < 8; ++c) {
            float xv[9][3];
            #pragma unroll
            for (int ly = 0; ly < 9; ++ly)
                #pragma unroll
                for (int s = 0; s < 3; ++s)
                    xv[ly][s] = Xl[c][ly][wc + s];
            float wvv[4][9];
            #pragma unroll
            for (int i = 0; i < 4; ++i)
                #pragma unroll
                for (int t = 0; t < 9; ++t)
                    wvv[i][t] = Wl[og * 4 + i][c * 9 + t];
            #pragma unroll
            for (int i = 0; i < 4; ++i)
                #pragma unroll
                for (int j = 0; j < 7; ++j)
                    #pragma unroll
                    for (int r = 0; r < 3; ++r)
                        #pragma unroll
                        for (int s = 0; s < 3; ++s)
                            acc[i][j] = fmaf(wvv[i][r * 3 + s], xv[j + r][s], acc[i][j]);
        }
        __syncthreads();
    }

    if (w < 56) {
        #pragma unroll
        for (int i = 0; i < 4; ++i) {
            int o = o_base + og * 4 + i;
            float bb = bias[kb * NOC + o];
            #pragma unroll
            for (int j = 0; j < 7; ++j)
                out[(((size_t)b * NOC + o) * NH + (row_base + j)) * NW + w] = acc[i][j] + bb;
        }
    }
}

extern "C" void kernel_launch(void* const* d_in, const int* in_sizes, int n_in,
                              void* d_out, int out_size, void* d_ws, size_t ws_size,
                              hipStream_t stream) {
    const float* x      = (const float*)d_in[0];
    const float* w_fc1  = (const float*)d_in[1];
    const float* w_fc2  = (const float*)d_in[2];
    const float* b_fc2  = (const float*)d_in[3];
    const float* weight = (const float*)d_in[4];
    const float* bias   = (const float*)d_in[5];
    float* out = (float*)d_out;
    float* ws  = (float*)d_ws;

    if (ws_size >= WS_NEED) {
        hipLaunchKernelGGL(k_prep, dim3(1152), dim3(256), 0, stream, x, weight, ws, out);
        hipLaunchKernelGGL(k_mid, dim3(144), dim3(256), 0, stream,
                           w_fc1, w_fc2, b_fc2, weight, ws, out, out + OUT0);
        hipLaunchKernelGGL(k_conv_mfma, dim3(512), dim3(512), 0, stream, bias, ws, out);
    } else {
        hipLaunchKernelGGL(k_pool, dim3(NB * NC), dim3(256), 0, stream, x, ws);
        hipLaunchKernelGGL(k_fc, dim3(1), dim3(256), 0, stream,
                           w_fc1, w_fc2, b_fc2, ws, out + OUT0);
        hipLaunchKernelGGL(k_maxtanh, dim3(256), dim3(256), 0, stream, weight, ws);
        hipLaunchKernelGGL(k_quant, dim3(512), dim3(256), 0, stream, weight, ws);
        hipLaunchKernelGGL(k_conv, dim3(16, 8, NB), dim3(256), 0, stream, x, bias, ws, out);
    }
}

// Round 9
// 182.856 us; speedup vs baseline: 1.1925x; 1.0206x over previous
//
#include <hip/hip_runtime.h>
#include <math.h>

#define NB 16
#define NC 256
#define NH 56
#define NW 56
#define NHW 3136
#define NHID 65
#define NK 4
#define NOC 256
#define WN 589824            // 256*256*9
#define OUT0 12845056        // 16*256*56*56

// ws header (float indices)
#define WS_POOLED 0          // [4096] (fallback path only)
#define WS_KB     4096       // [16] ints
#define WS_MAX    4112       // [1] (fallback path only)
#define WS_MAXP   4128       // [256] non-atomic maxtanh partials (mfma path)
#define WS_WQF    8192       // fallback fp32 banks [4][WN]
// byte offsets (MFMA path)
#define ZSL_OFF   24576ul    // 1920 B zero slab (border rows) - inside header
#define WQB_OFF   32768ul    // bf16 packed A-frags [4][8 ot][8 cs][18 f][64 lane][8] = 4,718,592 B
#define XP_OFF    4751360ul  // bf16 [16 cs][16 b][56 row][1920 B swizzled slab] = 27,525,120 B
#define WS_NEED   32325632ul
// pooling partials in OUT scratch: [b][y][c] fp32 = 917,504 B (conv overwrites later)

typedef unsigned int u32;
typedef unsigned short u16;
typedef unsigned long long u64;
typedef __attribute__((ext_vector_type(8))) short s8v;
typedef __attribute__((ext_vector_type(16))) float f16v;

__device__ __forceinline__ u16 f2bf(float f) {
    union { float f; u32 u; } v; v.f = f;
    u32 u = v.u;
    return (u16)((u + 0x7fffu + ((u >> 16) & 1u)) >> 16);
}

__device__ __forceinline__ void gload_lds16(const void* g, void* l) {
    __builtin_amdgcn_global_load_lds((const __attribute__((address_space(1))) u32*)g,
                                     (__attribute__((address_space(3))) u32*)l, 16, 0, 0);
}

// bank-swizzled byte offset of (padded col, channel-half) inside a 1920 B row slab
__device__ __forceinline__ int xswz(int col, int hf) {
    return (col * 32 + hf * 16) ^ (((col >> 2) & 7) << 4);
}

// ---------------- MFMA path: 3 kernels ----------------

// k_prep: grid 1152 x 256.
//  blocks 0..895  : (b*56+y) transpose ONE row -> xp (channel-chunk-outer, bank-swizzled)
//                   + per-row channel sums -> scratch[b][y][c]
//  blocks 896..1151: maxtanh partials -> ws[WS_MAXP + j]
__global__ __launch_bounds__(256) void k_prep(const float* __restrict__ x,
                                              const float* __restrict__ w,
                                              float* __restrict__ ws,
                                              float* __restrict__ scratch) {
    const int tid = threadIdx.x;
    if (blockIdx.x >= 896) {                     // maxtanh partial
        int j = blockIdx.x - 896;
        float m = 0.f;
        for (int i = j * 256 + tid; i < WN; i += 65536)
            m = fmaxf(m, fabsf(tanhf(w[i])));
        for (int off = 32; off > 0; off >>= 1) m = fmaxf(m, __shfl_down(m, off, 64));
        __shared__ float part[4];
        int lane = tid & 63, wv = tid >> 6;
        if (lane == 0) part[wv] = m;
        __syncthreads();
        if (tid == 0)
            ws[WS_MAXP + j] = fmaxf(fmaxf(part[0], part[1]), fmaxf(part[2], part[3]));
        return;
    }
    const int by = blockIdx.x;                   // b*56 + y
    const int b = by / 56, y = by % 56;
    const int c16 = tid >> 4, q = tid & 15;      // 16 channels x 16 q-lanes
    __shared__ __align__(16) u16 Lbt[56 * 264];  // [w][c] pitch 264
    __shared__ float pl[256];

    #pragma unroll
    for (int ci = 0; ci < 16; ++ci) {            // 16 independent iterations -> deep MLP
        int c = ci * 16 + c16;
        float4 v = make_float4(0.f, 0.f, 0.f, 0.f);
        if (q < 14) {
            v = *(const float4*)(x + ((size_t)(b * 256 + c)) * NHW + (size_t)y * 56 + q * 4);
            Lbt[(q * 4 + 0) * 264 + c] = f2bf(v.x);
            Lbt[(q * 4 + 1) * 264 + c] = f2bf(v.y);
            Lbt[(q * 4 + 2) * 264 + c] = f2bf(v.z);
            Lbt[(q * 4 + 3) * 264 + c] = f2bf(v.w);
        }
        float s = v.x + v.y + v.z + v.w;
        s += __shfl_down(s, 8, 16);
        s += __shfl_down(s, 4, 16);
        s += __shfl_down(s, 2, 16);
        s += __shfl_down(s, 1, 16);
        if (q == 0) pl[c] = s;
    }
    __syncthreads();
    scratch[(size_t)by * 256 + tid] = pl[tid];   // coalesced 1KB store

    // swizzled 16B-granule writes: xp[cs][b][y][1920B]; col 0/57 are zero borders
    char* xpn = (char*)ws + XP_OFF;
    #pragma unroll 1
    for (int g = tid; g < 16 * 58 * 2; g += 256) {
        int cs = g / 116, rm = g - cs * 116;
        int col = rm >> 1, hf = rm & 1;
        s8v v = (s8v)0;
        if (col >= 1 && col <= 56)
            v = *(const s8v*)(Lbt + (col - 1) * 264 + cs * 16 + hf * 8);
        *(s8v*)(xpn + (((size_t)cs * 16 + b) * 56 + y) * 1920 + xswz(col, hf)) = v;
    }
    if (by == 0) {                               // zero slab for border rows (once)
        u64* z = (u64*)((char*)ws + ZSL_OFF);
        for (int i = tid; i < 240; i += 256) z[i] = 0ull;
    }
}

// k_mid: grid 144 x 256. blocks 0..15: fc+argmax; 16..143: quant+pack.
__global__ __launch_bounds__(256) void k_mid(const float* __restrict__ w_fc1,
                                             const float* __restrict__ w_fc2,
                                             const float* __restrict__ b_fc2,
                                             const float* __restrict__ w,
                                             float* __restrict__ ws,
                                             const float* __restrict__ scratch,
                                             float* __restrict__ out_raw) {
    const int tid = threadIdx.x;
    if (blockIdx.x < 16) {                       // ---- fc ----
        const int b = blockIdx.x;
        __shared__ float pl[NC];
        __shared__ float hs[NHID];
        __shared__ float raws[NK];
        float p = 0.f;
        for (int y = 0; y < 56; ++y)             // coalesced across threads per y
            p += scratch[((size_t)(b * 56 + y)) * 256 + tid];
        pl[tid] = p * (1.0f / NHW);
        __syncthreads();
        if (tid < NHID) {
            float s = 0.f;
            for (int c = 0; c < NC; ++c) s = fmaf(pl[c], w_fc1[tid * NC + c], s);
            hs[tid] = fmaxf(s, 0.f);
        }
        __syncthreads();
        if (tid < NK) {
            float s = b_fc2[tid];
            for (int j = 0; j < NHID; ++j) s = fmaf(hs[j], w_fc2[tid * NHID + j], s);
            raws[tid] = s;
            out_raw[b * NK + tid] = s;
        }
        __syncthreads();
        if (tid == 0) {
            int best = 0;
            for (int k = 1; k < NK; ++k) if (raws[k] > raws[best]) best = k;
            ((int*)(ws + WS_KB))[b] = best;
        }
        return;
    }
    // ---- quant + pack ----
    __shared__ float mred[4];
    float mv = ws[WS_MAXP + tid];
    for (int off = 32; off > 0; off >>= 1) mv = fmaxf(mv, __shfl_down(mv, off, 64));
    if ((tid & 63) == 0) mred[tid >> 6] = mv;
    __syncthreads();
    const float maxt = fmaxf(fmaxf(mred[0], mred[1]), fmaxf(mred[2], mred[3]));

    u16* wqp = (u16*)((char*)ws + WQB_OFF);
    int idx = (blockIdx.x - 16) * 256 + tid;     // 128 blocks: 256 o x 128 c2
    int o = idx >> 7, c2 = idx & 127;
    int ch0 = c2 * 2;
    int cs = ch0 >> 5, cc = ch0 & 31;
    int ks2 = cc >> 4, hf = (cc >> 3) & 1, j = cc & 7;
    int n = o & 31, ot = o >> 5;
    const float* wp = w + ((size_t)o * 256 + ch0) * 9;
    float t0[9], t1[9];
    #pragma unroll
    for (int t = 0; t < 9; ++t) t0[t] = tanhf(wp[t]);
    #pragma unroll
    for (int t = 0; t < 9; ++t) t1[t] = tanhf(wp[9 + t]);
    #pragma unroll
    for (int bank = 0; bank < 4; ++bank) {
        float a = (float)(4 << bank);
        #pragma unroll
        for (int tap = 0; tap < 9; ++tap) {
            float xq0 = (t0[tap] / maxt + 1.f) * 0.5f;
            float xq1 = (t1[tap] / maxt + 1.f) * 0.5f;
            float q0 = fminf(floorf(a * xq0), a - 1.f) / a * 2.f - 1.f;
            float q1 = fminf(floorf(a * xq1), a - 1.f) / a * 2.f - 1.f;
            u32 pk = (u32)f2bf(q0) | ((u32)f2bf(q1) << 16);
            size_t off16 = ((((size_t)((bank * 8 + ot) * 8 + cs)) * 18 + tap * 2 + ks2) * 64
                            + hf * 32 + n) * 8 + j;
            *(u32*)(wqp + off16) = pk;
        }
    }
}

// Implicit-GEMM conv, mfma_f32_32x32x16_bf16.
// v8: coalesced X staging. v4/v5/v7 all pinned at ~10.8k cy/step with LDS
// (4.4k) + MFMA (3.8k) unexplained residual ~2.6k, invariant across schedule
// and occupancy. Hidden constant identified: X gload_lds had per-lane stride
// 512B -> 64 scattered 16B L2 requests per instruction (~2.3k req/CU-step),
// a serial VMEM-address cost no SQ/TCC counter shows. xp is now channel-
// chunk-outer [cs][b][row][1920B swizzled slab]: staging = src + lane*16,
// fully coalesced (1KB/instr); bank-swizzle baked into the GLOBAL layout
// (pre-swizzled source + swizzled ds_read, rule #21) keeps B-reads
// conflict-free. Border rows 0/57 redirect to a zero slab; row slab staged
// as 2x1KB loads overlapping 128B (same-value double write, benign).
// Schedule/waves/vmcnt/setprio identical to v7.
__global__ __launch_bounds__(512, 4) void k_conv_mfma(const float* __restrict__ bias,
                                                      const float* __restrict__ ws_f,
                                                      float* __restrict__ out) {
    const int L = blockIdx.x;
    const int xcd = L & 7, slot = L >> 3;        // XCD-chunked swizzle (512 % 8 == 0)
    const int oq = slot >> 4;                    // 0..3
    const int pair = xcd * 16 + (slot & 15);     // b*8 + strip
    const int b = pair >> 3, strip = pair & 7;
    const int r0 = strip * 7;
    const int tid = threadIdx.x;
    const int wv = tid >> 6, lane = tid & 63;
    const int n = lane & 31, hf = lane >> 5;
    const int vw = (wv + (slot & 7)) & 7;        // rotate tile roles across blocks
    const int ntile = (vw < 5) ? 2 : 1;
    const int t0 = (vw < 5) ? vw * 2 : 10 + (vw - 5);
    const int kb = ((const int*)(ws_f + WS_KB))[b];
    const u16* wqp = (const u16*)((const char*)ws_f + WQB_OFF);
    const char* xpn = (const char*)ws_f + XP_OFF;
    const char* zsl = (const char*)ws_f + ZSL_OFF;

    __shared__ __align__(16) u16 Xl[2][9216];    // [buf][9 row][2048B slab] = 2x18 KB
    __shared__ __align__(16) u16 Al[2][9216];    // [buf][2 tile][9 tap][64 lane][8] = 2x18 KB

    int bofs[2][3];                              // pr*2048 + swz(pc+s, hf)
    #pragma unroll
    for (int t = 0; t < 2; ++t) {
        int p = (t0 + t) * 32 + n;
        if (t >= ntile || p > 391) p = 391;      // clamp: in-bounds dummy read
        int pr = p / 56, pc = p - pr * 56;
        #pragma unroll
        for (int s = 0; s < 3; ++s)
            bofs[t][s] = pr * 2048 + xswz(pc + s, hf);
    }
    const u16* ab0 = wqp + (size_t)((kb * 8 + oq * 2 + 0) * 8) * (18 * 64 * 8);
    const u16* ab1 = wqp + (size_t)((kb * 8 + oq * 2 + 1) * 8) * (18 * 64 * 8);

    f16v acc0[2], acc1[2];
    #pragma unroll
    for (int t = 0; t < 2; ++t) { acc0[t] = (f16v)0.f; acc1[t] = (f16v)0.f; }

    // 36 segs per step: X = 9 rows x 2 halves (1KB each, overlap 128B), A = 18.
    // Waves stage {5,5,5,5,4,4,4,4}.
    const int sbase = (wv < 4) ? wv * 5 : 20 + (wv - 4) * 4;
    const int scnt  = (wv < 4) ? 5 : 4;
#define STAGE(stn, bn)                                                                   \
    {                                                                                    \
        const int csn = (stn) >> 1, ksn = (stn) & 1;                                     \
        _Pragma("unroll")                                                                \
        for (int i = 0; i < 5; ++i)                                                      \
            if (i < scnt) {                                                              \
                int seg = sbase + i;                                                     \
                if (seg < 18) {                                                          \
                    int row = seg >> 1, half = seg & 1;                                  \
                    int rr = r0 + row;                                                   \
                    const char* src = (rr >= 1 && rr <= 56)                              \
                        ? xpn + (((size_t)(stn) * 16 + b) * 56 + (rr - 1)) * 1920        \
                        : zsl;                                                           \
                    gload_lds16(src + half * 896 + lane * 16,                            \
                                (void*)(&Xl[bn][row * 1024 + half * 448]));              \
                } else {                                                                 \
                    int aa = seg - 18;                                                   \
                    int tile = (aa >= 9) ? 1 : 0;                                        \
                    int tap = aa - tile * 9;                                             \
                    const u16* ab = tile ? ab1 : ab0;                                    \
                    gload_lds16(ab + (size_t)(csn * 18 + tap * 2 + ksn) * 512 + lane * 8, \
                                (void*)(&Al[bn][aa * 512]));                             \
                }                                                                        \
            }                                                                            \
    }

    STAGE(0, 0);                                 // scnt loads in flight

    #pragma unroll 1
    for (int st = 0; st < 16; ++st) {
        int pb = st & 1;
        if (st < 15) {
            STAGE(st + 1, pb ^ 1);               // +scnt -> <=2*scnt outstanding
            // wait only stage(st)'s scnt; stage(st+1)'s stay in flight across barrier
            if (wv < 4) { asm volatile("s_waitcnt vmcnt(5)" ::: "memory"); }
            else        { asm volatile("s_waitcnt vmcnt(4)" ::: "memory"); }
        } else {
            asm volatile("s_waitcnt vmcnt(0)" ::: "memory");
        }
        __builtin_amdgcn_s_barrier();            // buf[pb] staged & visible
        __builtin_amdgcn_s_setprio(1);
        const u16* AB = &Al[pb][0];
        const char* XB = (const char*)&Xl[pb][0];
        #pragma unroll
        for (int tap = 0; tap < 9; ++tap) {
            s8v a0 = *(const s8v*)(AB + tap * 512 + lane * 8);
            s8v a1 = *(const s8v*)(AB + (9 + tap) * 512 + lane * 8);
            const int r = tap / 3, s = tap % 3;
            const int coff = r * 2048;
            #pragma unroll
            for (int t = 0; t < 2; ++t)
                if (t < ntile) {
                    s8v bf = *(const s8v*)(XB + bofs[t][s] + coff);
                    acc0[t] = __builtin_amdgcn_mfma_f32_32x32x16_bf16(a0, bf, acc0[t], 0, 0, 0);
                    acc1[t] = __builtin_amdgcn_mfma_f32_32x32x16_bf16(a1, bf, acc1[t], 0, 0, 0);
                }
        }
        __builtin_amdgcn_s_setprio(0);
        asm volatile("" ::: "memory");
        __builtin_amdgcn_s_barrier();            // all reads of buf[pb] done -> st+2 may overwrite
    }
#undef STAGE

    #pragma unroll
    for (int t = 0; t < 2; ++t)
        if (t < ntile) {
            int p = (t0 + t) * 32 + n;
            if (p < 392) {
                int pr = p / 56, pc = p - pr * 56;
                float* op = out + (size_t)b * 256 * NHW + (size_t)(r0 + pr) * 56 + pc;
                #pragma unroll
                for (int reg = 0; reg < 16; ++reg) {
                    int m = (reg & 3) + 8 * (reg >> 2) + 4 * hf;
                    int o0 = oq * 64 + m;
                    op[(size_t)o0 * NHW] = acc0[t][reg] + bias[kb * NOC + o0];
                    op[(size_t)(o0 + 32) * NHW] = acc1[t][reg] + bias[kb * NOC + o0 + 32];
                }
            }
        }
}

// ---------------- fallback fp32 path ----------------

__global__ __launch_bounds__(256) void k_pool(const float* __restrict__ x,
                                              float* __restrict__ ws) {
    int plane = blockIdx.x;
    const float* p = x + (size_t)plane * NHW;
    float s = 0.f;
    for (int i = threadIdx.x; i < NHW; i += 256) s += p[i];
    for (int off = 32; off > 0; off >>= 1) s += __shfl_down(s, off, 64);
    __shared__ float part[4];
    int lane = threadIdx.x & 63, wv = threadIdx.x >> 6;
    if (lane == 0) part[wv] = s;
    __syncthreads();
    if (threadIdx.x == 0)
        ws[WS_POOLED + plane] = part[0] + part[1] + part[2] + part[3];
}

__global__ __launch_bounds__(256) void k_fc(const float* __restrict__ w_fc1,
                                            const float* __restrict__ w_fc2,
                                            const float* __restrict__ b_fc2,
                                            float* __restrict__ ws,
                                            float* __restrict__ out_raw) {
    __shared__ float pl[NB * NC];
    __shared__ float hs[NB][NHID];
    __shared__ float raws[NB][NK];
    for (int i = threadIdx.x; i < NB * NC; i += 256)
        pl[i] = ws[WS_POOLED + i] * (1.0f / NHW);
    __syncthreads();
    for (int idx = threadIdx.x; idx < NB * NHID; idx += 256) {
        int b = idx / NHID, j = idx % NHID;
        float s = 0.f;
        for (int c = 0; c < NC; ++c) s = fmaf(pl[b * NC + c], w_fc1[j * NC + c], s);
        hs[b][j] = fmaxf(s, 0.f);
    }
    __syncthreads();
    if (threadIdx.x < NB * NK) {
        int b = threadIdx.x / NK, k = threadIdx.x % NK;
        float s = b_fc2[k];
        for (int j = 0; j < NHID; ++j) s = fmaf(hs[b][j], w_fc2[k * NHID + j], s);
        raws[b][k] = s;
        out_raw[b * NK + k] = s;
    }
    __syncthreads();
    if (threadIdx.x < NB) {
        int best = 0;
        for (int k = 1; k < NK; ++k)
            if (raws[threadIdx.x][k] > raws[threadIdx.x][best]) best = k;
        ((int*)(ws + WS_KB))[threadIdx.x] = best;
    }
}

__global__ __launch_bounds__(256) void k_maxtanh(const float* __restrict__ w,
                                                 float* __restrict__ ws) {
    float m = 0.f;
    for (int i = blockIdx.x * 256 + threadIdx.x; i < WN; i += gridDim.x * 256)
        m = fmaxf(m, fabsf(tanhf(w[i])));
    for (int off = 32; off > 0; off >>= 1) m = fmaxf(m, __shfl_down(m, off, 64));
    __shared__ float part[4];
    int lane = threadIdx.x & 63, wv = threadIdx.x >> 6;
    if (lane == 0) part[wv] = m;
    __syncthreads();
    if (threadIdx.x == 0) {
        float t = fmaxf(fmaxf(part[0], part[1]), fmaxf(part[2], part[3]));
        atomicMax((unsigned int*)ws + WS_MAX, __float_as_uint(t));
    }
}

__global__ __launch_bounds__(256) void k_quant(const float* __restrict__ w,
                                               float* __restrict__ ws) {
    float maxt = __uint_as_float(((const unsigned int*)ws)[WS_MAX]);
    float* wqf = ws + WS_WQF;
    for (int i = blockIdx.x * 256 + threadIdx.x; i < WN; i += gridDim.x * 256) {
        float t = tanhf(w[i]);
        float xq = (t / maxt + 1.0f) * 0.5f;
        #pragma unroll
        for (int k = 0; k < NK; ++k) {
            float a = (float)(4 << k);
            float q = fminf(floorf(a * xq), a - 1.0f) / a;
            wqf[(size_t)k * WN + i] = q * 2.0f - 1.0f;
        }
    }
}

__global__ __launch_bounds__(256) void k_conv(const float* __restrict__ x,
                                              const float* __restrict__ bias,
                                              const float* __restrict__ ws,
                                              float* __restrict__ out) {
    const int o_base = blockIdx.x * 16;
    const int row_base = blockIdx.y * 7;
    const int b = blockIdx.z;
    const int tid = threadIdx.x;
    const int w = tid & 63;
    const int og = tid >> 6;
    const int wc = (w < 56) ? w : 55;
    const int kb = ((const int*)(ws + WS_KB))[b];
    const float* wqf = ws + WS_WQF + (size_t)kb * WN;

    __shared__ float Xl[8][9][58];
    __shared__ float Wl[16][72];

    float acc[4][7];
    #pragma unroll
    for (int i = 0; i < 4; ++i)
        #pragma unroll
        for (int j = 0; j < 7; ++j) acc[i][j] = 0.f;

    for (int c0 = 0; c0 < NC; c0 += 8) {
        for (int idx = tid; idx < 1152; idx += 256) {
            int o = idx / 72, rem = idx - o * 72;
            Wl[o][rem] = wqf[(size_t)(o_base + o) * 2304 + c0 * 9 + rem];
        }
        for (int idx = tid; idx < 4176; idx += 256) {
            int c = idx / 522, rem = idx - c * 522;
            int ly = rem / 58, lx = rem - ly * 58;
            int gy = row_base - 1 + ly, gx = lx - 1;
            float v = 0.f;
            if (gy >= 0 && gy < NH && (unsigned)gx < (unsigned)NW)
                v = x[(((size_t)b * NC + c0 + c) * NH + gy) * NW + gx];
            Xl[c][ly][lx] = v;
        }
        __syncthreads();
        #pragma unroll 1
        for (int c = 0; c < 8; ++c) {
            float xv[9][3];
            #pragma unroll
            for (int ly = 0; ly < 9; ++ly)
                #pragma unroll
                for (int s = 0; s < 3; ++s)
                    xv[ly][s] = Xl[c][ly][wc + s];
            float wvv[4][9];
            #pragma unroll
            for (int i = 0; i < 4; ++i)
                #pragma unroll
                for (int t = 0; t < 9; ++t)
                    wvv[i][t] = Wl[og * 4 + i][c * 9 + t];
            #pragma unroll
            for (int i = 0; i < 4; ++i)
                #pragma unroll
                for (int j = 0; j < 7; ++j)
                    #pragma unroll
                    for (int r = 0; r < 3; ++r)
                        #pragma unroll
                        for (int s = 0; s < 3; ++s)
                            acc[i][j] = fmaf(wvv[i][r * 3 + s], xv[j + r][s], acc[i][j]);
        }
        __syncthreads();
    }

    if (w < 56) {
        #pragma unroll
        for (int i = 0; i < 4; ++i) {
            int o = o_base + og * 4 + i;
            float bb = bias[kb * NOC + o];
            #pragma unroll
            for (int j = 0; j < 7; ++j)
                out[(((size_t)b * NOC + o) * NH + (row_base + j)) * NW + w] = acc[i][j] + bb;
        }
    }
}

extern "C" void kernel_launch(void* const* d_in, const int* in_sizes, int n_in,
                              void* d_out, int out_size, void* d_ws, size_t ws_size,
                              hipStream_t stream) {
    const float* x      = (const float*)d_in[0];
    const float* w_fc1  = (const float*)d_in[1];
    const float* w_fc2  = (const float*)d_in[2];
    const float* b_fc2  = (const float*)d_in[3];
    const float* weight = (const float*)d_in[4];
    const float* bias   = (const float*)d_in[5];
    float* out = (float*)d_out;
    float* ws  = (float*)d_ws;

    if (ws_size >= WS_NEED) {
        hipLaunchKernelGGL(k_prep, dim3(1152), dim3(256), 0, stream, x, weight, ws, out);
        hipLaunchKernelGGL(k_mid, dim3(144), dim3(256), 0, stream,
                           w_fc1, w_fc2, b_fc2, weight, ws, out, out + OUT0);
        hipLaunchKernelGGL(k_conv_mfma, dim3(512), dim3(512), 0, stream, bias, ws, out);
    } else {
        hipLaunchKernelGGL(k_pool, dim3(NB * NC), dim3(256), 0, stream, x, ws);
        hipLaunchKernelGGL(k_fc, dim3(1), dim3(256), 0, stream,
                           w_fc1, w_fc2, b_fc2, ws, out + OUT0);
        hipLaunchKernelGGL(k_maxtanh, dim3(256), dim3(256), 0, stream, weight, ws);
        hipLaunchKernelGGL(k_quant, dim3(512), dim3(256), 0, stream, weight, ws);
        hipLaunchKernelGGL(k_conv, dim3(16, 8, NB), dim3(256), 0, stream, x, bias, ws, out);
    }
}

// Round 10
// 180.032 us; speedup vs baseline: 1.2112x; 1.0157x over previous
//
#include <hip/hip_runtime.h>
#include <math.h>

#define NB 16
#define NC 256
#define NH 56
#define NW 56
#define NHW 3136
#define NHID 65
#define NK 4
#define NOC 256
#define WN 589824            // 256*256*9
#define OUT0 12845056        // 16*256*56*56

// ws header (float indices)
#define WS_POOLED 0          // [4096] (fallback path only)
#define WS_KB     4096       // [16] ints
#define WS_MAX    4112       // [1] (fallback path only)
#define WS_MAXP   4128       // [256] non-atomic maxtanh partials (mfma path)
#define WS_WQF    8192       // fallback fp32 banks [4][WN]
// byte offsets (MFMA path)
#define ZSL_OFF   24576ul    // 2048 B zero slab (border rows) - inside header
#define WQB_OFF   32768ul    // bf16 packed A-frags [4][8 ot][8 cs][18 f][64 lane][8] = 4,718,592 B
#define XP_OFF    4751360ul  // bf16 [16 cs][16 b][56 row][1920 B slab: hf0 cols|hf1 cols|pad]
#define WS_NEED   32325632ul
// pooling partials in OUT scratch: [b][y][c] fp32 = 917,504 B (conv overwrites later)

typedef unsigned int u32;
typedef unsigned short u16;
typedef unsigned long long u64;
typedef __attribute__((ext_vector_type(8))) short s8v;
typedef __attribute__((ext_vector_type(16))) float f16v;

__device__ __forceinline__ u16 f2bf(float f) {
    union { float f; u32 u; } v; v.f = f;
    u32 u = v.u;
    return (u16)((u + 0x7fffu + ((u >> 16) & 1u)) >> 16);
}

__device__ __forceinline__ void gload_lds16(const void* g, void* l) {
    __builtin_amdgcn_global_load_lds((const __attribute__((address_space(1))) u32*)g,
                                     (__attribute__((address_space(3))) u32*)l, 16, 0, 0);
}

// ---------------- MFMA path: 3 kernels ----------------

// k_prep: grid 1152 x 256.
//  blocks 0..895  : (b*56+y) transpose ONE row -> xp (channel-chunk-outer, linear slab)
//                   + per-row channel sums -> scratch[b][y][c]
//  blocks 896..1151: maxtanh partials -> ws[WS_MAXP + j]
__global__ __launch_bounds__(256) void k_prep(const float* __restrict__ x,
                                              const float* __restrict__ w,
                                              float* __restrict__ ws,
                                              float* __restrict__ scratch) {
    const int tid = threadIdx.x;
    if (blockIdx.x >= 896) {                     // maxtanh partial
        int j = blockIdx.x - 896;
        float m = 0.f;
        for (int i = j * 256 + tid; i < WN; i += 65536)
            m = fmaxf(m, fabsf(tanhf(w[i])));
        for (int off = 32; off > 0; off >>= 1) m = fmaxf(m, __shfl_down(m, off, 64));
        __shared__ float part[4];
        int lane = tid & 63, wv = tid >> 6;
        if (lane == 0) part[wv] = m;
        __syncthreads();
        if (tid == 0)
            ws[WS_MAXP + j] = fmaxf(fmaxf(part[0], part[1]), fmaxf(part[2], part[3]));
        return;
    }
    const int by = blockIdx.x;                   // b*56 + y
    const int b = by / 56, y = by % 56;
    const int c16 = tid >> 4, q = tid & 15;      // 16 channels x 16 q-lanes
    __shared__ __align__(16) u16 Lbt[56 * 264];  // [w][c] pitch 264
    __shared__ float pl[256];

    #pragma unroll
    for (int ci = 0; ci < 16; ++ci) {            // 16 independent iterations -> deep MLP
        int c = ci * 16 + c16;
        float4 v = make_float4(0.f, 0.f, 0.f, 0.f);
        if (q < 14) {
            v = *(const float4*)(x + ((size_t)(b * 256 + c)) * NHW + (size_t)y * 56 + q * 4);
            Lbt[(q * 4 + 0) * 264 + c] = f2bf(v.x);
            Lbt[(q * 4 + 1) * 264 + c] = f2bf(v.y);
            Lbt[(q * 4 + 2) * 264 + c] = f2bf(v.z);
            Lbt[(q * 4 + 3) * 264 + c] = f2bf(v.w);
        }
        float s = v.x + v.y + v.z + v.w;
        s += __shfl_down(s, 8, 16);
        s += __shfl_down(s, 4, 16);
        s += __shfl_down(s, 2, 16);
        s += __shfl_down(s, 1, 16);
        if (q == 0) pl[c] = s;
    }
    __syncthreads();
    scratch[(size_t)by * 256 + tid] = pl[tid];   // coalesced 1KB store

    // linear 16B-granule writes: xp[cs][b][y][1920B slab]
    // slab granules: g<58 = hf0 col g; 58<=g<116 = hf1 col g-58; 116..119 = zero pad
    char* xpn = (char*)ws + XP_OFF;
    #pragma unroll 1
    for (int g = tid; g < 16 * 120; g += 256) {
        int cs = g / 120, gg = g - cs * 120;
        s8v v = (s8v)0;
        if (gg < 116) {
            int hf = (gg >= 58) ? 1 : 0;
            int col = gg - hf * 58;
            if (col >= 1 && col <= 56)
                v = *(const s8v*)(Lbt + (col - 1) * 264 + cs * 16 + hf * 8);
        }
        *(s8v*)(xpn + (((size_t)cs * 16 + b) * 56 + y) * 1920 + gg * 16) = v;
    }
    if (by == 0) {                               // zero slab for border rows (once)
        u64* z = (u64*)((char*)ws + ZSL_OFF);
        for (int i = tid; i < 256; i += 256) z[i] = 0ull;
    }
}

// k_mid: grid 144 x 256. blocks 0..15: fc+argmax; 16..143: quant+pack.
__global__ __launch_bounds__(256) void k_mid(const float* __restrict__ w_fc1,
                                             const float* __restrict__ w_fc2,
                                             const float* __restrict__ b_fc2,
                                             const float* __restrict__ w,
                                             float* __restrict__ ws,
                                             const float* __restrict__ scratch,
                                             float* __restrict__ out_raw) {
    const int tid = threadIdx.x;
    if (blockIdx.x < 16) {                       // ---- fc ----
        const int b = blockIdx.x;
        __shared__ float pl[NC];
        __shared__ float hs[NHID];
        __shared__ float raws[NK];
        float p = 0.f;
        for (int y = 0; y < 56; ++y)             // coalesced across threads per y
            p += scratch[((size_t)(b * 56 + y)) * 256 + tid];
        pl[tid] = p * (1.0f / NHW);
        __syncthreads();
        if (tid < NHID) {
            float s = 0.f;
            for (int c = 0; c < NC; ++c) s = fmaf(pl[c], w_fc1[tid * NC + c], s);
            hs[tid] = fmaxf(s, 0.f);
        }
        __syncthreads();
        if (tid < NK) {
            float s = b_fc2[tid];
            for (int j = 0; j < NHID; ++j) s = fmaf(hs[j], w_fc2[tid * NHID + j], s);
            raws[tid] = s;
            out_raw[b * NK + tid] = s;
        }
        __syncthreads();
        if (tid == 0) {
            int best = 0;
            for (int k = 1; k < NK; ++k) if (raws[k] > raws[best]) best = k;
            ((int*)(ws + WS_KB))[b] = best;
        }
        return;
    }
    // ---- quant + pack ----
    __shared__ float mred[4];
    float mv = ws[WS_MAXP + tid];
    for (int off = 32; off > 0; off >>= 1) mv = fmaxf(mv, __shfl_down(mv, off, 64));
    if ((tid & 63) == 0) mred[tid >> 6] = mv;
    __syncthreads();
    const float maxt = fmaxf(fmaxf(mred[0], mred[1]), fmaxf(mred[2], mred[3]));

    u16* wqp = (u16*)((char*)ws + WQB_OFF);
    int idx = (blockIdx.x - 16) * 256 + tid;     // 128 blocks: 256 o x 128 c2
    int o = idx >> 7, c2 = idx & 127;
    int ch0 = c2 * 2;
    int cs = ch0 >> 5, cc = ch0 & 31;
    int ks2 = cc >> 4, hf = (cc >> 3) & 1, j = cc & 7;
    int n = o & 31, ot = o >> 5;
    const float* wp = w + ((size_t)o * 256 + ch0) * 9;
    float t0[9], t1[9];
    #pragma unroll
    for (int t = 0; t < 9; ++t) t0[t] = tanhf(wp[t]);
    #pragma unroll
    for (int t = 0; t < 9; ++t) t1[t] = tanhf(wp[9 + t]);
    #pragma unroll
    for (int bank = 0; bank < 4; ++bank) {
        float a = (float)(4 << bank);
        #pragma unroll
        for (int tap = 0; tap < 9; ++tap) {
            float xq0 = (t0[tap] / maxt + 1.f) * 0.5f;
            float xq1 = (t1[tap] / maxt + 1.f) * 0.5f;
            float q0 = fminf(floorf(a * xq0), a - 1.f) / a * 2.f - 1.f;
            float q1 = fminf(floorf(a * xq1), a - 1.f) / a * 2.f - 1.f;
            u32 pk = (u32)f2bf(q0) | ((u32)f2bf(q1) << 16);
            size_t off16 = ((((size_t)((bank * 8 + ot) * 8 + cs)) * 18 + tap * 2 + ks2) * 64
                            + hf * 32 + n) * 8 + j;
            *(u32*)(wqp + off16) = pk;
        }
    }
}

// Implicit-GEMM conv, mfma_f32_32x32x16_bf16.
// v9: coalesced staging (v8's win, kept) WITHOUT the bank-swizzle (v8's loss,
// reverted). v8 A/B: coalescing gained ~1000 cy/block-step but the XOR swizzle
// mapped 32 consecutive cols onto 8 bank-starts x 4 lanes = 4-way conflicts
// (SQ_LDS_BANK_CONFLICT 1.47M -> 6.73M, 16% of kernel cycles). v7's plain
// [hf*1024 + col*16] LDS image measured 1.47M -> reproduce it EXACTLY, but
// from a linear global slab [hf0 cols | hf1 cols | pad] so staging stays
// two contiguous 1KB gload_lds per row (src +0 -> LDS+0, src +928 -> LDS+1024;
// 6-granule tail overrun lands in never-read LDS padding, stays inside ws).
// Schedule/waves/vmcnt/setprio identical to v7/v8.
__global__ __launch_bounds__(512, 4) void k_conv_mfma(const float* __restrict__ bias,
                                                      const float* __restrict__ ws_f,
                                                      float* __restrict__ out) {
    const int L = blockIdx.x;
    const int xcd = L & 7, slot = L >> 3;        // XCD-chunked swizzle (512 % 8 == 0)
    const int oq = slot >> 4;                    // 0..3
    const int pair = xcd * 16 + (slot & 15);     // b*8 + strip
    const int b = pair >> 3, strip = pair & 7;
    const int r0 = strip * 7;
    const int tid = threadIdx.x;
    const int wv = tid >> 6, lane = tid & 63;
    const int n = lane & 31, hf = lane >> 5;
    const int vw = (wv + (slot & 7)) & 7;        // rotate tile roles across blocks
    const int ntile = (vw < 5) ? 2 : 1;
    const int t0 = (vw < 5) ? vw * 2 : 10 + (vw - 5);
    const int kb = ((const int*)(ws_f + WS_KB))[b];
    const u16* wqp = (const u16*)((const char*)ws_f + WQB_OFF);
    const char* xpn = (const char*)ws_f + XP_OFF;
    const char* zsl = (const char*)ws_f + ZSL_OFF;

    __shared__ __align__(16) u16 Xl[2][9216];    // [buf][9 row][2048B: hf*1024 + col*16]
    __shared__ __align__(16) u16 Al[2][9216];    // [buf][2 tile][9 tap][64 lane][8] = 2x18 KB

    int bofs[2];
    #pragma unroll
    for (int t = 0; t < 2; ++t) {
        int p = (t0 + t) * 32 + n;
        if (t >= ntile || p > 391) p = 391;      // clamp: in-bounds dummy read
        int pr = p / 56, pc = p - pr * 56;
        bofs[t] = pr * 2048 + hf * 1024 + pc * 16;
    }
    const u16* ab0 = wqp + (size_t)((kb * 8 + oq * 2 + 0) * 8) * (18 * 64 * 8);
    const u16* ab1 = wqp + (size_t)((kb * 8 + oq * 2 + 1) * 8) * (18 * 64 * 8);

    f16v acc0[2], acc1[2];
    #pragma unroll
    for (int t = 0; t < 2; ++t) { acc0[t] = (f16v)0.f; acc1[t] = (f16v)0.f; }

    // 36 segs per step: X = 9 rows x 2 halves (1KB contiguous each), A = 18.
    // Waves stage {5,5,5,5,4,4,4,4}.
    const int sbase = (wv < 4) ? wv * 5 : 20 + (wv - 4) * 4;
    const int scnt  = (wv < 4) ? 5 : 4;
#define STAGE(stn, bn)                                                                   \
    {                                                                                    \
        const int csn = (stn) >> 1, ksn = (stn) & 1;                                     \
        _Pragma("unroll")                                                                \
        for (int i = 0; i < 5; ++i)                                                      \
            if (i < scnt) {                                                              \
                int seg = sbase + i;                                                     \
                if (seg < 18) {                                                          \
                    int row = seg >> 1, half = seg & 1;                                  \
                    int rr = r0 + row;                                                   \
                    const char* src = (rr >= 1 && rr <= 56)                              \
                        ? xpn + (((size_t)(stn) * 16 + b) * 56 + (rr - 1)) * 1920        \
                        : zsl;                                                           \
                    gload_lds16(src + half * 928 + lane * 16,                            \
                                (void*)(&Xl[bn][row * 1024 + half * 512]));              \
                } else {                                                                 \
                    int aa = seg - 18;                                                   \
                    int tile = (aa >= 9) ? 1 : 0;                                        \
                    int tap = aa - tile * 9;                                             \
                    const u16* ab = tile ? ab1 : ab0;                                    \
                    gload_lds16(ab + (size_t)(csn * 18 + tap * 2 + ksn) * 512 + lane * 8, \
                                (void*)(&Al[bn][aa * 512]));                             \
                }                                                                        \
            }                                                                            \
    }

    STAGE(0, 0);                                 // scnt loads in flight

    #pragma unroll 1
    for (int st = 0; st < 16; ++st) {
        int pb = st & 1;
        if (st < 15) {
            STAGE(st + 1, pb ^ 1);               // +scnt -> <=2*scnt outstanding
            // wait only stage(st)'s scnt; stage(st+1)'s stay in flight across barrier
            if (wv < 4) { asm volatile("s_waitcnt vmcnt(5)" ::: "memory"); }
            else        { asm volatile("s_waitcnt vmcnt(4)" ::: "memory"); }
        } else {
            asm volatile("s_waitcnt vmcnt(0)" ::: "memory");
        }
        __builtin_amdgcn_s_barrier();            // buf[pb] staged & visible
        __builtin_amdgcn_s_setprio(1);
        const u16* AB = &Al[pb][0];
        const char* XB = (const char*)&Xl[pb][0];
        #pragma unroll
        for (int tap = 0; tap < 9; ++tap) {
            s8v a0 = *(const s8v*)(AB + tap * 512 + lane * 8);
            s8v a1 = *(const s8v*)(AB + (9 + tap) * 512 + lane * 8);
            const int r = tap / 3, s = tap % 3;
            const int coff = r * 2048 + s * 16;
            #pragma unroll
            for (int t = 0; t < 2; ++t)
                if (t < ntile) {
                    s8v bf = *(const s8v*)(XB + bofs[t] + coff);
                    acc0[t] = __builtin_amdgcn_mfma_f32_32x32x16_bf16(a0, bf, acc0[t], 0, 0, 0);
                    acc1[t] = __builtin_amdgcn_mfma_f32_32x32x16_bf16(a1, bf, acc1[t], 0, 0, 0);
                }
        }
        __builtin_amdgcn_s_setprio(0);
        asm volatile("" ::: "memory");
        __builtin_amdgcn_s_barrier();            // all reads of buf[pb] done -> st+2 may overwrite
    }
#undef STAGE

    #pragma unroll
    for (int t = 0; t < 2; ++t)
        if (t < ntile) {
            int p = (t0 + t) * 32 + n;
            if (p < 392) {
                int pr = p / 56, pc = p - pr * 56;
                float* op = out + (size_t)b * 256 * NHW + (size_t)(r0 + pr) * 56 + pc;
                #pragma unroll
                for (int reg = 0; reg < 16; ++reg) {
                    int m = (reg & 3) + 8 * (reg >> 2) + 4 * hf;
                    int o0 = oq * 64 + m;
                    op[(size_t)o0 * NHW] = acc0[t][reg] + bias[kb * NOC + o0];
                    op[(size_t)(o0 + 32) * NHW] = acc1[t][reg] + bias[kb * NOC + o0 + 32];
                }
            }
        }
}

// ---------------- fallback fp32 path ----------------

__global__ __launch_bounds__(256) void k_pool(const float* __restrict__ x,
                                              float* __restrict__ ws) {
    int plane = blockIdx.x;
    const float* p = x + (size_t)plane * NHW;
    float s = 0.f;
    for (int i = threadIdx.x; i < NHW; i += 256) s += p[i];
    for (int off = 32; off > 0; off >>= 1) s += __shfl_down(s, off, 64);
    __shared__ float part[4];
    int lane = threadIdx.x & 63, wv = threadIdx.x >> 6;
    if (lane == 0) part[wv] = s;
    __syncthreads();
    if (threadIdx.x == 0)
        ws[WS_POOLED + plane] = part[0] + part[1] + part[2] + part[3];
}

__global__ __launch_bounds__(256) void k_fc(const float* __restrict__ w_fc1,
                                            const float* __restrict__ w_fc2,
                                            const float* __restrict__ b_fc2,
                                            float* __restrict__ ws,
                                            float* __restrict__ out_raw) {
    __shared__ float pl[NB * NC];
    __shared__ float hs[NB][NHID];
    __shared__ float raws[NB][NK];
    for (int i = threadIdx.x; i < NB * NC; i += 256)
        pl[i] = ws[WS_POOLED + i] * (1.0f / NHW);
    __syncthreads();
    for (int idx = threadIdx.x; idx < NB * NHID; idx += 256) {
        int b = idx / NHID, j = idx % NHID;
        float s = 0.f;
        for (int c = 0; c < NC; ++c) s = fmaf(pl[b * NC + c], w_fc1[j * NC + c], s);
        hs[b][j] = fmaxf(s, 0.f);
    }
    __syncthreads();
    if (threadIdx.x < NB * NK) {
        int b = threadIdx.x / NK, k = threadIdx.x % NK;
        float s = b_fc2[k];
        for (int j = 0; j < NHID; ++j) s = fmaf(hs[b][j], w_fc2[k * NHID + j], s);
        raws[b][k] = s;
        out_raw[b * NK + k] = s;
    }
    __syncthreads();
    if (threadIdx.x < NB) {
        int best = 0;
        for (int k = 1; k < NK; ++k)
            if (raws[threadIdx.x][k] > raws[threadIdx.x][best]) best = k;
        ((int*)(ws + WS_KB))[threadIdx.x] = best;
    }
}

__global__ __launch_bounds__(256) void k_maxtanh(const float* __restrict__ w,
                                                 float* __restrict__ ws) {
    float m = 0.f;
    for (int i = blockIdx.x * 256 + threadIdx.x; i < WN; i += gridDim.x * 256)
        m = fmaxf(m, fabsf(tanhf(w[i])));
    for (int off = 32; off > 0; off >>= 1) m = fmaxf(m, __shfl_down(m, off, 64));
    __shared__ float part[4];
    int lane = threadIdx.x & 63, wv = threadIdx.x >> 6;
    if (lane == 0) part[wv] = m;
    __syncthreads();
    if (threadIdx.x == 0) {
        float t = fmaxf(fmaxf(part[0], part[1]), fmaxf(part[2], part[3]));
        atomicMax((unsigned int*)ws + WS_MAX, __float_as_uint(t));
    }
}

__global__ __launch_bounds__(256) void k_quant(const float* __restrict__ w,
                                               float* __restrict__ ws) {
    float maxt = __uint_as_float(((const unsigned int*)ws)[WS_MAX]);
    float* wqf = ws + WS_WQF;
    for (int i = blockIdx.x * 256 + threadIdx.x; i < WN; i += gridDim.x * 256) {
        float t = tanhf(w[i]);
        float xq = (t / maxt + 1.0f) * 0.5f;
        #pragma unroll
        for (int k = 0; k < NK; ++k) {
            float a = (float)(4 << k);
            float q = fminf(floorf(a * xq), a - 1.0f) / a;
            wqf[(size_t)k * WN + i] = q * 2.0f - 1.0f;
        }
    }
}

__global__ __launch_bounds__(256) void k_conv(const float* __restrict__ x,
                                              const float* __restrict__ bias,
                                              const float* __restrict__ ws,
                                              float* __restrict__ out) {
    const int o_base = blockIdx.x * 16;
    const int row_base = blockIdx.y * 7;
    const int b = blockIdx.z;
    const int tid = threadIdx.x;
    const int w = tid & 63;
    const int og = tid >> 6;
    const int wc = (w < 56) ? w : 55;
    const int kb = ((const int*)(ws + WS_KB))[b];
    const float* wqf = ws + WS_WQF + (size_t)kb * WN;

    __shared__ float Xl[8][9][58];
    __shared__ float Wl[16][72];

    float acc[4][7];
    #pragma unroll
    for (int i = 0; i < 4; ++i)
        #pragma unroll
        for (int j = 0; j < 7; ++j) acc[i][j] = 0.f;

    for (int c0 = 0; c0 < NC; c0 += 8) {
        for (int idx = tid; idx < 1152; idx += 256) {
            int o = idx / 72, rem = idx - o * 72;
            Wl[o][rem] = wqf[(size_t)(o_base + o) * 2304 + c0 * 9 + rem];
        }
        for (int idx = tid; idx < 4176; idx += 256) {
            int c = idx / 522, rem = idx - c * 522;
            int ly = rem / 58, lx = rem - ly * 58;
            int gy = row_base - 1 + ly, gx = lx - 1;
            float v = 0.f;
            if (gy >= 0 && gy < NH && (unsigned)gx < (unsigned)NW)
                v = x[(((size_t)b * NC + c0 + c) * NH + gy) * NW + gx];
            Xl[c][ly][lx] = v;
        }
        __syncthreads();
        #pragma unroll 1
        for (int c = 0; c < 8; ++c) {
            float xv[9][3];
            #pragma unroll
            for (int ly = 0; ly < 9; ++ly)
                #pragma unroll
                for (int s = 0; s < 3; ++s)
                    xv[ly][s] = Xl[c][ly][wc + s];
            float wvv[4][9];
            #pragma unroll
            for (int i = 0; i < 4; ++i)
                #pragma unroll
                for (int t = 0; t < 9; ++t)
                    wvv[i][t] = Wl[og * 4 + i][c * 9 + t];
            #pragma unroll
            for (int i = 0; i < 4; ++i)
                #pragma unroll
                for (int j = 0; j < 7; ++j)
                    #pragma unroll
                    for (int r = 0; r < 3; ++r)
                        #pragma unroll
                        for (int s = 0; s < 3; ++s)
                            acc[i][j] = fmaf(wvv[i][r * 3 + s], xv[j + r][s], acc[i][j]);
        }
        __syncthreads();
    }

    if (w < 56) {
        #pragma unroll
        for (int i = 0; i < 4; ++i) {
            int o = o_base + og * 4 + i;
            float bb = bias[kb * NOC + o];
            #pragma unroll
            for (int j = 0; j < 7; ++j)
                out[(((size_t)b * NOC + o) * NH + (row_base + j)) * NW + w] = acc[i][j] + bb;
        }
    }
}

extern "C" void kernel_launch(void* const* d_in, const int* in_sizes, int n_in,
                              void* d_out, int out_size, void* d_ws, size_t ws_size,
                              hipStream_t stream) {
    const float* x      = (const float*)d_in[0];
    const float* w_fc1  = (const float*)d_in[1];
    const float* w_fc2  = (const float*)d_in[2];
    const float* b_fc2  = (const float*)d_in[3];
    const float* weight = (const float*)d_in[4];
    const float* bias   = (const float*)d_in[5];
    float* out = (float*)d_out;
    float* ws  = (float*)d_ws;

    if (ws_size >= WS_NEED) {
        hipLaunchKernelGGL(k_prep, dim3(1152), dim3(256), 0, stream, x, weight, ws, out);
        hipLaunchKernelGGL(k_mid, dim3(144), dim3(256), 0, stream,
                           w_fc1, w_fc2, b_fc2, weight, ws, out, out + OUT0);
        hipLaunchKernelGGL(k_conv_mfma, dim3(512), dim3(512), 0, stream, bias, ws, out);
    } else {
        hipLaunchKernelGGL(k_pool, dim3(NB * NC), dim3(256), 0, stream, x, ws);
        hipLaunchKernelGGL(k_fc, dim3(1), dim3(256), 0, stream,
                           w_fc1, w_fc2, b_fc2, ws, out + OUT0);
        hipLaunchKernelGGL(k_maxtanh, dim3(256), dim3(256), 0, stream, weight, ws);
        hipLaunchKernelGGL(k_quant, dim3(512), dim3(256), 0, stream, weight, ws);
        hipLaunchKernelGGL(k_conv, dim3(16, 8, NB), dim3(256), 0, stream, x, bias, ws, out);
    }
}